// Round 10
// baseline (402.338 us; speedup 1.0000x reference)
//
#include <hip/hip_runtime.h>
#include <hip/hip_bf16.h>
#include <stdint.h>

// ---------------------------------------------------------------------------
// 2-layer GAT (inference) on MI355X, dtype-adaptive.
// Round-10 changes vs round-9 (394 us):
//  * softmax_den4/softmax_den1 fused INTO aggregate4/aggregate1: per-edge
//    weight recomputed in-line (uniform as[sn] load + max(v,0.2v) + exp);
//    denominator accumulates identically in all lanes of a head group (no
//    reduction). wbuf (12.8 MB write + re-read) eliminated. 2 fewer kernels.
//  * gather loop unroll 4 -> 8.
// GEMM+att fusion, CSR build, scans, casts unchanged from round 9.
// ---------------------------------------------------------------------------

typedef __attribute__((ext_vector_type(8))) short bf16x8;
typedef __attribute__((ext_vector_type(4))) float f32x4;

__device__ __forceinline__ float bf2f(__hip_bfloat16 v) { return __bfloat162float(v); }
__device__ __forceinline__ float bfbits2f(unsigned short s) {
  union { uint32_t u; float f; } v; v.u = ((uint32_t)s) << 16; return v.f;
}
__device__ __forceinline__ unsigned short f2bfbits(float f) {
  union { float f; uint32_t u; } v; v.f = f;
  uint32_t u = v.u;
  return (unsigned short)((u + 0x7fffu + ((u >> 16) & 1u)) >> 16);  // RNE
}

template <bool BF>
__device__ __forceinline__ float loadF(const void* p, size_t i) {
  if (BF) return bf2f(((const __hip_bfloat16*)p)[i]);
  return ((const float*)p)[i];
}
template <bool BF>
__device__ __forceinline__ void storeF(void* p, size_t i, float v) {
  if (BF) ((__hip_bfloat16*)p)[i] = __float2bfloat16(v);
  else    ((float*)p)[i] = v;
}
template <bool I64>
__device__ __forceinline__ int loadI(const void* p, size_t i) {
  if (I64) return (int)((const long long*)p)[i];
  return ((const int*)p)[i];
}
__device__ __forceinline__ float lrelu(float v) { return fmaxf(v, 0.2f * v); }

// ----------------- dtype detection (1 thread) ------------------------------
__global__ void detect_kernel(const uint32_t* __restrict__ xbits,
                              const uint32_t* __restrict__ eibits,
                              int* __restrict__ flags) {
  if (threadIdx.x != 0 || blockIdx.x != 0) return;
  int plausible = 0;
  for (int i = 0; i < 64; i++) {
    uint32_t u = xbits[i];
    uint32_t e = (u >> 23) & 0xffu;
    if ((e < 160u && e > 90u) || (u & 0x7fffffffu) == 0u) plausible++;
  }
  flags[0] = (plausible < 32) ? 1 : 0;  // 1 = floats are bf16
  int allz = 1;
  for (int i = 0; i < 64; i++)
    if (eibits[2 * i + 1] != 0u) allz = 0;
  flags[1] = allz;                      // 1 = edge_index is int64
}

// ----------------- prep: cast x to bf16 bits -------------------------------
__global__ __launch_bounds__(256) void cast_to_bf16(const void* __restrict__ in,
                                                    unsigned short* __restrict__ out,
                                                    size_t n, const int* __restrict__ flags) {
  size_t i = ((size_t)blockIdx.x * 256 + threadIdx.x) * 4;
  if (i >= n) return;
  ushort4 o;
  if (flags[0]) {
    o = *(const ushort4*)((const unsigned short*)in + i);
  } else {
    float4 v = *(const float4*)((const float*)in + i);
    o.x = f2bfbits(v.x); o.y = f2bfbits(v.y);
    o.z = f2bfbits(v.z); o.w = f2bfbits(v.w);
  }
  *(ushort4*)(out + i) = o;
}

// ----------------- prep: W[K][N] -> WT[N][K] bf16 bits ---------------------
__global__ __launch_bounds__(256) void transpose_cast(const void* __restrict__ W,
                                                      unsigned short* __restrict__ WT,
                                                      int K, int N,
                                                      const int* __restrict__ flags) {
  int idx = blockIdx.x * 256 + threadIdx.x;
  if (idx >= K * N) return;
  int k = idx / N, n = idx - k * N;
  float v = flags[0] ? loadF<true>(W, idx) : loadF<false>(W, idx);
  WT[(size_t)n * K + k] = f2bfbits(v);
}

// ----------------- MFMA GEMM + fused attention-dot epilogue ----------------
template <int NT, int H>
__global__ __launch_bounds__(256) void gemm_mfma_att(
    const unsigned short* __restrict__ A,   // [M][K] bf16 bits
    const unsigned short* __restrict__ BT,  // [NT*16][K] bf16 bits
    unsigned short* __restrict__ C,         // [M][NT*16] bf16 bits
    const void* __restrict__ att_s, const void* __restrict__ att_d,
    float* __restrict__ as_o, float* __restrict__ ad_o,
    float* __restrict__ wself_o,
    int M, int K, const int* __restrict__ flags) {
  const int NCOL = NT * 16;
  const int lane = threadIdx.x & 63;
  const int col = lane & 15;
  const int quad = lane >> 4;
  const int m0 = blockIdx.x * 64 + (threadIdx.x >> 6) * 16;

  int gm = m0 + col;                 // A row this lane supplies
  if (gm > M - 1) gm = M - 1;        // clamp: garbage only affects guarded rows
  const unsigned short* arow = A + (size_t)gm * K + quad * 8;

  f32x4 acc[NT] = {};
  for (int k0 = 0; k0 < K; k0 += 32) {
    bf16x8 a = *(const bf16x8*)(arow + k0);
#pragma unroll
    for (int s = 0; s < NT; s++) {
      bf16x8 b = *(const bf16x8*)(BT + (size_t)(s * 16 + col) * K + quad * 8 + k0);
      acc[s] = __builtin_amdgcn_mfma_f32_16x16x32_bf16(a, b, acc[s], 0, 0, 0);
    }
  }
  // store C
#pragma unroll
  for (int s = 0; s < NT; s++)
#pragma unroll
    for (int r = 0; r < 4; r++) {
      int m = m0 + quad * 4 + r;
      if (m < M) C[(size_t)m * NCOL + s * 16 + col] = f2bfbits(acc[s][r]);
    }
  // fused attention dots
  const bool f = flags[0] != 0;
#pragma unroll
  for (int h = 0; h < H; h++) {
    float ps[4] = {0.f, 0.f, 0.f, 0.f};
    float pd[4] = {0.f, 0.f, 0.f, 0.f};
#pragma unroll
    for (int j = 0; j < NT / H; j++) {
      int s = h * (NT / H) + j;
      int ci = s * 16 + col;
      float av = f ? loadF<true>(att_s, ci) : loadF<false>(att_s, ci);
      float dv = f ? loadF<true>(att_d, ci) : loadF<false>(att_d, ci);
#pragma unroll
      for (int r = 0; r < 4; r++) {
        ps[r] += acc[s][r] * av;
        pd[r] += acc[s][r] * dv;
      }
    }
#pragma unroll
    for (int o = 1; o < 16; o <<= 1) {
#pragma unroll
      for (int r = 0; r < 4; r++) {
        ps[r] += __shfl_xor(ps[r], o);
        pd[r] += __shfl_xor(pd[r], o);
      }
    }
    if (col == 0) {
#pragma unroll
      for (int r = 0; r < 4; r++) {
        int m = m0 + quad * 4 + r;
        if (m < M) {
          as_o[m * H + h] = ps[r];
          ad_o[m * H + h] = pd[r];
          wself_o[m * H + h] = __expf(lrelu(ps[r] + pd[r]));  // no max-sub
        }
      }
    }
  }
}

// ----------------- CSR build ------------------------------------------------
__global__ void hist_kernel(const void* __restrict__ ei, int E,
                            int* __restrict__ deg, const int* __restrict__ flags) {
  int e = blockIdx.x * blockDim.x + threadIdx.x;
  if (e >= E) return;
  int d = flags[1] ? loadI<true>(ei, (size_t)E + e) : loadI<false>(ei, (size_t)E + e);
  atomicAdd(&deg[d], 1);
}

__global__ __launch_bounds__(256) void scan_block_sums(const int* __restrict__ deg,
                                                       int* __restrict__ bsum, int n) {
  __shared__ int buf[256];
  const int t = threadIdx.x;
  const int i = blockIdx.x * 256 + t;
  buf[t] = (i < n) ? deg[i] : 0;
  __syncthreads();
  for (int o = 128; o > 0; o >>= 1) {
    if (t < o) buf[t] += buf[t + o];
    __syncthreads();
  }
  if (t == 0) bsum[blockIdx.x] = buf[0];
}

__global__ __launch_bounds__(256) void scan_bsums(int* __restrict__ bsum, int nb) {
  __shared__ int buf[256];
  const int t = threadIdx.x;
  int orig = (t < nb) ? bsum[t] : 0;
  buf[t] = orig;
  __syncthreads();
  for (int o = 1; o < 256; o <<= 1) {
    int v = (t >= o) ? buf[t - o] : 0;
    __syncthreads();
    buf[t] += v;
    __syncthreads();
  }
  if (t < nb) bsum[t] = buf[t] - orig;  // exclusive
}

__global__ __launch_bounds__(256) void scan_finalize(const int* __restrict__ deg,
                                                     const int* __restrict__ bsum,
                                                     int* __restrict__ row_start, int n) {
  __shared__ int buf[256];
  const int t = threadIdx.x;
  const int i = blockIdx.x * 256 + t;
  int v = (i < n) ? deg[i] : 0;
  buf[t] = v;
  __syncthreads();
  for (int o = 1; o < 256; o <<= 1) {
    int x = (t >= o) ? buf[t - o] : 0;
    __syncthreads();
    buf[t] += x;
    __syncthreads();
  }
  if (i < n) row_start[i + 1] = bsum[blockIdx.x] + buf[t];
  if (i == 0) row_start[0] = 0;
}

__global__ void scatter_edges(const void* __restrict__ ei, int E,
                              const int* __restrict__ row_start,
                              int* __restrict__ cursor, int* __restrict__ col_src,
                              const int* __restrict__ flags) {
  int e = blockIdx.x * blockDim.x + threadIdx.x;
  if (e >= E) return;
  int s, d;
  if (flags[1]) { s = loadI<true>(ei, e);  d = loadI<true>(ei, (size_t)E + e); }
  else          { s = loadI<false>(ei, e); d = loadI<false>(ei, (size_t)E + e); }
  int pos = atomicAdd(&cursor[d], 1);
  col_src[row_start[d] + pos] = s;
}

// ----------------- fused softmax + aggregation -----------------------------
// H=4: one wave per dst covers all 4 heads. Lane l -> channels 4l..4l+3
// (head = l>>4). Per edge: uniform as4[sn] load, per-lane head weight
// w = exp(max(v, 0.2v)); denominator p accumulates identically in all lanes
// of a head group (no reduction needed).
__global__ __launch_bounds__(256) void aggregate4f(
    const unsigned short* __restrict__ h_in,   // [N][256] bf16 bits
    const float* __restrict__ wselfA,          // [N*4]
    const float4* __restrict__ as4, const float4* __restrict__ ad4,
    const int* __restrict__ row_start, const int* __restrict__ col_src,
    const void* __restrict__ bias,
    unsigned short* __restrict__ out,          // [N][256] bf16 bits (x2)
    int N, const int* __restrict__ flags) {
  const int dst = blockIdx.x * 4 + (threadIdx.x >> 6);
  if (dst >= N) return;
  const int l = threadIdx.x & 63;
  const int h = l >> 4;
  const int rs = row_start[dst];
  const int dg = row_start[dst + 1] - rs;
  const float4 advv = ad4[dst];
  const float adh = (h == 0) ? advv.x : (h == 1) ? advv.y : (h == 2) ? advv.z : advv.w;
  const float ws = wselfA[dst * 4 + h];

  float a0, a1, a2, a3;
  {
    ushort4 sv = *(const ushort4*)(h_in + (size_t)dst * 256 + 4 * l);
    a0 = ws * bfbits2f(sv.x);
    a1 = ws * bfbits2f(sv.y);
    a2 = ws * bfbits2f(sv.z);
    a3 = ws * bfbits2f(sv.w);
  }
  float p = 0.f;
#pragma unroll 8
  for (int i = 0; i < dg; i++) {
    int sn = col_src[rs + i];
    float4 av = as4[sn];
    float ah = (h == 0) ? av.x : (h == 1) ? av.y : (h == 2) ? av.z : av.w;
    float v = ah + adh;
    float w = __expf(fmaxf(v, 0.2f * v));
    p += w;
    ushort4 sv = *(const ushort4*)(h_in + (size_t)sn * 256 + 4 * l);
    a0 += w * bfbits2f(sv.x);
    a1 += w * bfbits2f(sv.y);
    a2 += w * bfbits2f(sv.z);
    a3 += w * bfbits2f(sv.w);
  }
  const float inv = 1.0f / (p + ws + 1e-16f);
  const bool f = flags[0] != 0;
  float b0, b1, b2, b3;
  if (f) {
    b0 = loadF<true>(bias, 4 * l + 0); b1 = loadF<true>(bias, 4 * l + 1);
    b2 = loadF<true>(bias, 4 * l + 2); b3 = loadF<true>(bias, 4 * l + 3);
  } else {
    b0 = loadF<false>(bias, 4 * l + 0); b1 = loadF<false>(bias, 4 * l + 1);
    b2 = loadF<false>(bias, 4 * l + 2); b3 = loadF<false>(bias, 4 * l + 3);
  }
  float o0 = a0 * inv + b0, o1 = a1 * inv + b1;
  float o2 = a2 * inv + b2, o3 = a3 * inv + b3;
  o0 = o0 > 0.f ? o0 : __expf(o0) - 1.f;
  o1 = o1 > 0.f ? o1 : __expf(o1) - 1.f;
  o2 = o2 > 0.f ? o2 : __expf(o2) - 1.f;
  o3 = o3 > 0.f ? o3 : __expf(o3) - 1.f;
  ushort4 ov;
  ov.x = f2bfbits(o0); ov.y = f2bfbits(o1); ov.z = f2bfbits(o2); ov.w = f2bfbits(o3);
  *(ushort4*)(out + (size_t)dst * 256 + 4 * l) = ov;
}

// H=1: one wave per dst, lane = channel; per-edge weight inline (uniform).
__global__ __launch_bounds__(256) void aggregate1f(
    const unsigned short* __restrict__ h_in,   // [N][64] bf16 bits
    const float* __restrict__ wselfA,
    const float* __restrict__ as_, const float* __restrict__ ad_,
    const int* __restrict__ row_start, const int* __restrict__ col_src,
    const void* __restrict__ bias,
    void* __restrict__ out, int N, const int* __restrict__ flags) {
  const int dst = blockIdx.x * 4 + (threadIdx.x >> 6);
  if (dst >= N) return;
  const int l = threadIdx.x & 63;
  const int rs = row_start[dst];
  const int dg = row_start[dst + 1] - rs;
  const float adh = ad_[dst];
  const float ws = wselfA[dst];

  float acc = ws * bfbits2f(h_in[(size_t)dst * 64 + l]);
  float p = 0.f;
#pragma unroll 8
  for (int i = 0; i < dg; i++) {
    int sn = col_src[rs + i];
    float v = as_[sn] + adh;
    float w = __expf(fmaxf(v, 0.2f * v));
    p += w;
    acc += w * bfbits2f(h_in[(size_t)sn * 64 + l]);
  }
  const float inv = 1.0f / (p + ws + 1e-16f);
  const bool f = flags[0] != 0;
  float bv = f ? loadF<true>(bias, l) : loadF<false>(bias, l);
  float o = acc * inv + bv;
  size_t oi = (size_t)dst * 64 + l;
  if (f) storeF<true>(out, oi, o);
  else   storeF<false>(out, oi, o);
}

// ---------------------------------------------------------------------------
extern "C" void kernel_launch(void* const* d_in, const int* in_sizes, int n_in,
                              void* d_out, int out_size, void* d_ws, size_t ws_size,
                              hipStream_t stream) {
  const void* x    = d_in[0];
  const void* ei   = d_in[1];
  const void* W1   = d_in[2];
  const void* as1w = d_in[3];
  const void* ad1w = d_in[4];
  const void* b1   = d_in[5];
  const void* W2   = d_in[6];
  const void* as2w = d_in[7];
  const void* ad2w = d_in[8];
  const void* b2   = d_in[9];

  const int N  = out_size / 64;      // 50000
  const int F  = in_sizes[0] / N;    // 128
  const int E  = in_sizes[1] / 2;    // 800000
  const int H1 = in_sizes[3] / 64;   // 4
  const int D1 = H1 * 64;            // 256
  const int D2 = 64;                 // layer-2 output dim (H2 = 1)

  size_t off = 0;
  auto alloc = [&](size_t bytes) -> void* {
    void* p = (char*)d_ws + off;
    off += (bytes + 255) & ~(size_t)255;
    return p;
  };
  int* flags = (int*)alloc(2 * sizeof(int));
  __hip_bfloat16* h1 = (__hip_bfloat16*)alloc((size_t)N * D1 * 2);
  __hip_bfloat16* x2 = (__hip_bfloat16*)alloc((size_t)N * D1 * 2);
  __hip_bfloat16* h2 = h1;  // h1 dead after layer-1 aggregate; reuse
  unsigned short* xb  = (unsigned short*)alloc((size_t)N * F * 2);   // x in bf16
  unsigned short* w1t = (unsigned short*)alloc((size_t)D1 * F * 2);  // [256][128]
  unsigned short* w2t = (unsigned short*)alloc((size_t)D2 * D1 * 2); // [64][256]
  float* as1 = (float*)alloc((size_t)N * H1 * 4);
  float* ad1 = (float*)alloc((size_t)N * H1 * 4);
  float* wself1 = (float*)alloc((size_t)N * H1 * 4);
  float* as2 = (float*)alloc((size_t)N * 4);
  float* ad2 = (float*)alloc((size_t)N * 4);
  float* wself2 = (float*)alloc((size_t)N * 4);
  int* zero_region = (int*)alloc((size_t)2 * N * 4);  // deg | cursor
  int* deg = zero_region;
  int* cursor = zero_region + N;
  int* row_start = (int*)alloc((size_t)(N + 1) * 4);
  int* col_src = (int*)alloc((size_t)E * 4);
  int* bsum = (int*)alloc((size_t)256 * 4);
  (void)ws_size; (void)n_in;

  const int nb = (N + 255) / 256;
  const int eb = (E + 255) / 256;
  const int db = (N + 3) / 4;
  const int gb = (N + 63) / 64;

  // ---- dtype detection + CSR build + GEMM prep
  detect_kernel<<<1, 64, 0, stream>>>((const uint32_t*)x, (const uint32_t*)ei, flags);
  hipMemsetAsync(zero_region, 0, (size_t)2 * N * 4, stream);
  hist_kernel<<<eb, 256, 0, stream>>>(ei, E, deg, flags);
  scan_block_sums<<<nb, 256, 0, stream>>>(deg, bsum, N);
  scan_bsums<<<1, 256, 0, stream>>>(bsum, nb);
  scan_finalize<<<nb, 256, 0, stream>>>(deg, bsum, row_start, N);
  scatter_edges<<<eb, 256, 0, stream>>>(ei, E, row_start, cursor, col_src, flags);

  const size_t nx = (size_t)N * F;
  cast_to_bf16<<<(int)((nx / 4 + 255) / 256), 256, 0, stream>>>(x, xb, nx, flags);
  transpose_cast<<<(F * D1 + 255) / 256, 256, 0, stream>>>(W1, w1t, F, D1, flags);
  transpose_cast<<<(D1 * D2 + 255) / 256, 256, 0, stream>>>(W2, w2t, D1, D2, flags);

  // ---- layer 1: GEMM (64x256 tile) + fused att dots; fused softmax+gather
  gemm_mfma_att<16, 4><<<gb, 256, 0, stream>>>(
      xb, w1t, (unsigned short*)h1, as1w, ad1w, as1, ad1, wself1, N, F, flags);
  aggregate4f<<<db, 256, 0, stream>>>((const unsigned short*)h1, wself1,
                                      (const float4*)as1, (const float4*)ad1,
                                      row_start, col_src, b1,
                                      (unsigned short*)x2, N, flags);

  // ---- layer 2: GEMM (64x64 tile) + fused att dots; fused softmax+gather
  gemm_mfma_att<4, 1><<<gb, 256, 0, stream>>>(
      (const unsigned short*)x2, w2t, (unsigned short*)h2, as2w, ad2w,
      as2, ad2, wself2, N, D1, flags);
  aggregate1f<<<db, 256, 0, stream>>>((const unsigned short*)h2, wself2,
                                      as2, ad2, row_start, col_src, b2,
                                      d_out, N, flags);
}

// Round 11
// 397.238 us; speedup vs baseline: 1.0128x; 1.0128x over previous
//
#include <hip/hip_runtime.h>
#include <hip/hip_bf16.h>
#include <stdint.h>

// ---------------------------------------------------------------------------
// 2-layer GAT (inference) on MI355X, dtype-adaptive.
// Round-11 = revert to round-9 structure (394 us; round-10 fusion regressed:
// inline weight recompute put a random as4[sn] gather on the per-edge
// critical path -> latency-bound, 63->111 us). Deltas vs round 9:
//  * aggregate4 gather unroll 4 -> 8 (more outstanding row gathers).
//  * cast_to_bf16 + 2x transpose_cast merged into one prep_all dispatch.
// ---------------------------------------------------------------------------

typedef __attribute__((ext_vector_type(8))) short bf16x8;
typedef __attribute__((ext_vector_type(4))) float f32x4;

__device__ __forceinline__ float bf2f(__hip_bfloat16 v) { return __bfloat162float(v); }
__device__ __forceinline__ float bfbits2f(unsigned short s) {
  union { uint32_t u; float f; } v; v.u = ((uint32_t)s) << 16; return v.f;
}
__device__ __forceinline__ unsigned short f2bfbits(float f) {
  union { float f; uint32_t u; } v; v.f = f;
  uint32_t u = v.u;
  return (unsigned short)((u + 0x7fffu + ((u >> 16) & 1u)) >> 16);  // RNE
}

template <bool BF>
__device__ __forceinline__ float loadF(const void* p, size_t i) {
  if (BF) return bf2f(((const __hip_bfloat16*)p)[i]);
  return ((const float*)p)[i];
}
template <bool BF>
__device__ __forceinline__ void storeF(void* p, size_t i, float v) {
  if (BF) ((__hip_bfloat16*)p)[i] = __float2bfloat16(v);
  else    ((float*)p)[i] = v;
}
template <bool I64>
__device__ __forceinline__ int loadI(const void* p, size_t i) {
  if (I64) return (int)((const long long*)p)[i];
  return ((const int*)p)[i];
}
__device__ __forceinline__ float lrelu(float v) { return fmaxf(v, 0.2f * v); }

// ----------------- dtype detection (1 thread) ------------------------------
__global__ void detect_kernel(const uint32_t* __restrict__ xbits,
                              const uint32_t* __restrict__ eibits,
                              int* __restrict__ flags) {
  if (threadIdx.x != 0 || blockIdx.x != 0) return;
  int plausible = 0;
  for (int i = 0; i < 64; i++) {
    uint32_t u = xbits[i];
    uint32_t e = (u >> 23) & 0xffu;
    if ((e < 160u && e > 90u) || (u & 0x7fffffffu) == 0u) plausible++;
  }
  flags[0] = (plausible < 32) ? 1 : 0;  // 1 = floats are bf16
  int allz = 1;
  for (int i = 0; i < 64; i++)
    if (eibits[2 * i + 1] != 0u) allz = 0;
  flags[1] = allz;                      // 1 = edge_index is int64
}

// ----------------- prep (single dispatch): cast x; transpose W1, W2 --------
__global__ __launch_bounds__(256) void prep_all(
    const void* __restrict__ x, unsigned short* __restrict__ xb, size_t nx,
    const void* __restrict__ W1, unsigned short* __restrict__ w1t, int K1, int N1,
    const void* __restrict__ W2, unsigned short* __restrict__ w2t, int K2, int N2,
    int nb_cast, int nb_t1, const int* __restrict__ flags) {
  const int b = blockIdx.x;
  const bool f = flags[0] != 0;
  if (b < nb_cast) {
    size_t i = ((size_t)b * 256 + threadIdx.x) * 4;
    if (i >= nx) return;
    ushort4 o;
    if (f) {
      o = *(const ushort4*)((const unsigned short*)x + i);
    } else {
      float4 v = *(const float4*)((const float*)x + i);
      o.x = f2bfbits(v.x); o.y = f2bfbits(v.y);
      o.z = f2bfbits(v.z); o.w = f2bfbits(v.w);
    }
    *(ushort4*)(xb + i) = o;
  } else if (b < nb_cast + nb_t1) {
    int idx = (b - nb_cast) * 256 + threadIdx.x;
    if (idx >= K1 * N1) return;
    int k = idx / N1, n = idx - k * N1;
    float v = f ? loadF<true>(W1, idx) : loadF<false>(W1, idx);
    w1t[(size_t)n * K1 + k] = f2bfbits(v);
  } else {
    int idx = (b - nb_cast - nb_t1) * 256 + threadIdx.x;
    if (idx >= K2 * N2) return;
    int k = idx / N2, n = idx - k * N2;
    float v = f ? loadF<true>(W2, idx) : loadF<false>(W2, idx);
    w2t[(size_t)n * K2 + k] = f2bfbits(v);
  }
}

// ----------------- MFMA GEMM + fused attention-dot epilogue ----------------
template <int NT, int H>
__global__ __launch_bounds__(256) void gemm_mfma_att(
    const unsigned short* __restrict__ A,   // [M][K] bf16 bits
    const unsigned short* __restrict__ BT,  // [NT*16][K] bf16 bits
    unsigned short* __restrict__ C,         // [M][NT*16] bf16 bits
    const void* __restrict__ att_s, const void* __restrict__ att_d,
    float* __restrict__ as_o, float* __restrict__ ad_o,
    float* __restrict__ wself_o,
    int M, int K, const int* __restrict__ flags) {
  const int NCOL = NT * 16;
  const int lane = threadIdx.x & 63;
  const int col = lane & 15;
  const int quad = lane >> 4;
  const int m0 = blockIdx.x * 64 + (threadIdx.x >> 6) * 16;

  int gm = m0 + col;                 // A row this lane supplies
  if (gm > M - 1) gm = M - 1;        // clamp: garbage only affects guarded rows
  const unsigned short* arow = A + (size_t)gm * K + quad * 8;

  f32x4 acc[NT] = {};
  for (int k0 = 0; k0 < K; k0 += 32) {
    bf16x8 a = *(const bf16x8*)(arow + k0);
#pragma unroll
    for (int s = 0; s < NT; s++) {
      bf16x8 b = *(const bf16x8*)(BT + (size_t)(s * 16 + col) * K + quad * 8 + k0);
      acc[s] = __builtin_amdgcn_mfma_f32_16x16x32_bf16(a, b, acc[s], 0, 0, 0);
    }
  }
  // store C
#pragma unroll
  for (int s = 0; s < NT; s++)
#pragma unroll
    for (int r = 0; r < 4; r++) {
      int m = m0 + quad * 4 + r;
      if (m < M) C[(size_t)m * NCOL + s * 16 + col] = f2bfbits(acc[s][r]);
    }
  // fused attention dots
  const bool f = flags[0] != 0;
#pragma unroll
  for (int h = 0; h < H; h++) {
    float ps[4] = {0.f, 0.f, 0.f, 0.f};
    float pd[4] = {0.f, 0.f, 0.f, 0.f};
#pragma unroll
    for (int j = 0; j < NT / H; j++) {
      int s = h * (NT / H) + j;
      int ci = s * 16 + col;
      float av = f ? loadF<true>(att_s, ci) : loadF<false>(att_s, ci);
      float dv = f ? loadF<true>(att_d, ci) : loadF<false>(att_d, ci);
#pragma unroll
      for (int r = 0; r < 4; r++) {
        ps[r] += acc[s][r] * av;
        pd[r] += acc[s][r] * dv;
      }
    }
#pragma unroll
    for (int o = 1; o < 16; o <<= 1) {
#pragma unroll
      for (int r = 0; r < 4; r++) {
        ps[r] += __shfl_xor(ps[r], o);
        pd[r] += __shfl_xor(pd[r], o);
      }
    }
    if (col == 0) {
#pragma unroll
      for (int r = 0; r < 4; r++) {
        int m = m0 + quad * 4 + r;
        if (m < M) {
          as_o[m * H + h] = ps[r];
          ad_o[m * H + h] = pd[r];
          wself_o[m * H + h] = __expf(lrelu(ps[r] + pd[r]));  // no max-sub
        }
      }
    }
  }
}

// ----------------- CSR build ------------------------------------------------
__global__ void hist_kernel(const void* __restrict__ ei, int E,
                            int* __restrict__ deg, const int* __restrict__ flags) {
  int e = blockIdx.x * blockDim.x + threadIdx.x;
  if (e >= E) return;
  int d = flags[1] ? loadI<true>(ei, (size_t)E + e) : loadI<false>(ei, (size_t)E + e);
  atomicAdd(&deg[d], 1);
}

__global__ __launch_bounds__(256) void scan_block_sums(const int* __restrict__ deg,
                                                       int* __restrict__ bsum, int n) {
  __shared__ int buf[256];
  const int t = threadIdx.x;
  const int i = blockIdx.x * 256 + t;
  buf[t] = (i < n) ? deg[i] : 0;
  __syncthreads();
  for (int o = 128; o > 0; o >>= 1) {
    if (t < o) buf[t] += buf[t + o];
    __syncthreads();
  }
  if (t == 0) bsum[blockIdx.x] = buf[0];
}

__global__ __launch_bounds__(256) void scan_bsums(int* __restrict__ bsum, int nb) {
  __shared__ int buf[256];
  const int t = threadIdx.x;
  int orig = (t < nb) ? bsum[t] : 0;
  buf[t] = orig;
  __syncthreads();
  for (int o = 1; o < 256; o <<= 1) {
    int v = (t >= o) ? buf[t - o] : 0;
    __syncthreads();
    buf[t] += v;
    __syncthreads();
  }
  if (t < nb) bsum[t] = buf[t] - orig;  // exclusive
}

__global__ __launch_bounds__(256) void scan_finalize(const int* __restrict__ deg,
                                                     const int* __restrict__ bsum,
                                                     int* __restrict__ row_start, int n) {
  __shared__ int buf[256];
  const int t = threadIdx.x;
  const int i = blockIdx.x * 256 + t;
  int v = (i < n) ? deg[i] : 0;
  buf[t] = v;
  __syncthreads();
  for (int o = 1; o < 256; o <<= 1) {
    int x = (t >= o) ? buf[t - o] : 0;
    __syncthreads();
    buf[t] += x;
    __syncthreads();
  }
  if (i < n) row_start[i + 1] = bsum[blockIdx.x] + buf[t];
  if (i == 0) row_start[0] = 0;
}

__global__ void scatter_edges(const void* __restrict__ ei, int E,
                              const int* __restrict__ row_start,
                              int* __restrict__ cursor, int* __restrict__ col_src,
                              const int* __restrict__ flags) {
  int e = blockIdx.x * blockDim.x + threadIdx.x;
  if (e >= E) return;
  int s, d;
  if (flags[1]) { s = loadI<true>(ei, e);  d = loadI<true>(ei, (size_t)E + e); }
  else          { s = loadI<false>(ei, e); d = loadI<false>(ei, (size_t)E + e); }
  int pos = atomicAdd(&cursor[d], 1);
  col_src[row_start[d] + pos] = s;
}

// ----------------- per-dst softmax denominator (single sweep, no max) ------
__global__ __launch_bounds__(256) void softmax_den4(
    const float4* __restrict__ as4, const float4* __restrict__ ad4,
    const int* __restrict__ row_start, const int* __restrict__ col_src,
    const float4* __restrict__ wself4,
    float4* __restrict__ wbuf, float4* __restrict__ den4, int N) {
  const int dst = blockIdx.x * 4 + (threadIdx.x >> 6);
  if (dst >= N) return;
  const int l = threadIdx.x & 63;
  const int rs = row_start[dst];
  const int dg = row_start[dst + 1] - rs;
  const float4 adv = ad4[dst];

  float p0 = 0.f, p1 = 0.f, p2 = 0.f, p3 = 0.f;
  for (int base = 0; base < dg; base += 64) {
    int i = base + l;
    if (i < dg) {
      float4 a = as4[col_src[rs + i]];
      float4 w;
      w.x = __expf(lrelu(a.x + adv.x));
      w.y = __expf(lrelu(a.y + adv.y));
      w.z = __expf(lrelu(a.z + adv.z));
      w.w = __expf(lrelu(a.w + adv.w));
      wbuf[rs + i] = w;
      p0 += w.x; p1 += w.y; p2 += w.z; p3 += w.w;
    }
  }
#pragma unroll
  for (int o = 32; o > 0; o >>= 1) {
    p0 += __shfl_xor(p0, o);
    p1 += __shfl_xor(p1, o);
    p2 += __shfl_xor(p2, o);
    p3 += __shfl_xor(p3, o);
  }
  if (l == 0) {
    float4 ws = wself4[dst];
    float4 dn;
    dn.x = p0 + ws.x; dn.y = p1 + ws.y; dn.z = p2 + ws.z; dn.w = p3 + ws.w;
    den4[dst] = dn;
  }
}

__global__ __launch_bounds__(256) void softmax_den1(
    const float* __restrict__ as_, const float* __restrict__ ad_,
    const int* __restrict__ row_start, const int* __restrict__ col_src,
    const float* __restrict__ wself,
    float* __restrict__ wbuf, float* __restrict__ den, int N) {
  const int dst = blockIdx.x * 4 + (threadIdx.x >> 6);
  if (dst >= N) return;
  const int l = threadIdx.x & 63;
  const int rs = row_start[dst];
  const int dg = row_start[dst + 1] - rs;
  const float adv = ad_[dst];

  float p = 0.f;
  for (int base = 0; base < dg; base += 64) {
    int i = base + l;
    if (i < dg) {
      float w = __expf(lrelu(as_[col_src[rs + i]] + adv));
      wbuf[rs + i] = w;
      p += w;
    }
  }
#pragma unroll
  for (int o = 32; o > 0; o >>= 1) p += __shfl_xor(p, o);
  if (l == 0) den[dst] = p + wself[dst];
}

// ----------------- aggregation: pure weighted gather -----------------------
__global__ __launch_bounds__(256) void aggregate4(
    const unsigned short* __restrict__ h_in,   // [N][256] bf16 bits
    const float* __restrict__ wselfA, const float* __restrict__ denA,
    const float* __restrict__ wbuf,            // [E][4]
    const int* __restrict__ row_start, const int* __restrict__ col_src,
    const void* __restrict__ bias,
    unsigned short* __restrict__ out,          // [N][256] bf16 bits (x2)
    int N, const int* __restrict__ flags) {
  const int dst = blockIdx.x * 4 + (threadIdx.x >> 6);
  if (dst >= N) return;
  const int l = threadIdx.x & 63;
  const int h = l >> 4;
  const int rs = row_start[dst];
  const int dg = row_start[dst + 1] - rs;
  const float ws = wselfA[dst * 4 + h];
  const float inv = 1.0f / (denA[dst * 4 + h] + 1e-16f);

  float a0, a1, a2, a3;
  {
    ushort4 sv = *(const ushort4*)(h_in + (size_t)dst * 256 + 4 * l);
    a0 = ws * bfbits2f(sv.x);
    a1 = ws * bfbits2f(sv.y);
    a2 = ws * bfbits2f(sv.z);
    a3 = ws * bfbits2f(sv.w);
  }
#pragma unroll 8
  for (int i = 0; i < dg; i++) {
    int sn = col_src[rs + i];
    float w = wbuf[(size_t)(rs + i) * 4 + h];
    ushort4 sv = *(const ushort4*)(h_in + (size_t)sn * 256 + 4 * l);
    a0 += w * bfbits2f(sv.x);
    a1 += w * bfbits2f(sv.y);
    a2 += w * bfbits2f(sv.z);
    a3 += w * bfbits2f(sv.w);
  }
  const bool f = flags[0] != 0;
  float b0, b1, b2, b3;
  if (f) {
    b0 = loadF<true>(bias, 4 * l + 0); b1 = loadF<true>(bias, 4 * l + 1);
    b2 = loadF<true>(bias, 4 * l + 2); b3 = loadF<true>(bias, 4 * l + 3);
  } else {
    b0 = loadF<false>(bias, 4 * l + 0); b1 = loadF<false>(bias, 4 * l + 1);
    b2 = loadF<false>(bias, 4 * l + 2); b3 = loadF<false>(bias, 4 * l + 3);
  }
  float o0 = a0 * inv + b0, o1 = a1 * inv + b1;
  float o2 = a2 * inv + b2, o3 = a3 * inv + b3;
  o0 = o0 > 0.f ? o0 : __expf(o0) - 1.f;
  o1 = o1 > 0.f ? o1 : __expf(o1) - 1.f;
  o2 = o2 > 0.f ? o2 : __expf(o2) - 1.f;
  o3 = o3 > 0.f ? o3 : __expf(o3) - 1.f;
  ushort4 ov;
  ov.x = f2bfbits(o0); ov.y = f2bfbits(o1); ov.z = f2bfbits(o2); ov.w = f2bfbits(o3);
  *(ushort4*)(out + (size_t)dst * 256 + 4 * l) = ov;
}

__global__ __launch_bounds__(256) void aggregate1(
    const unsigned short* __restrict__ h_in,   // [N][64] bf16 bits
    const float* __restrict__ wselfA, const float* __restrict__ denA,
    const float* __restrict__ wbuf,            // [E]
    const int* __restrict__ row_start, const int* __restrict__ col_src,
    const void* __restrict__ bias,
    void* __restrict__ out, int N, const int* __restrict__ flags) {
  const int dst = blockIdx.x * 4 + (threadIdx.x >> 6);
  if (dst >= N) return;
  const int l = threadIdx.x & 63;
  const int rs = row_start[dst];
  const int dg = row_start[dst + 1] - rs;
  const float ws = wselfA[dst];
  const float inv = 1.0f / (denA[dst] + 1e-16f);

  float acc = ws * bfbits2f(h_in[(size_t)dst * 64 + l]);
#pragma unroll 8
  for (int i = 0; i < dg; i++) {
    int sn = col_src[rs + i];
    float w = wbuf[rs + i];
    acc += w * bfbits2f(h_in[(size_t)sn * 64 + l]);
  }
  const bool f = flags[0] != 0;
  float bv = f ? loadF<true>(bias, l) : loadF<false>(bias, l);
  float o = acc * inv + bv;
  size_t oi = (size_t)dst * 64 + l;
  if (f) storeF<true>(out, oi, o);
  else   storeF<false>(out, oi, o);
}

// ---------------------------------------------------------------------------
extern "C" void kernel_launch(void* const* d_in, const int* in_sizes, int n_in,
                              void* d_out, int out_size, void* d_ws, size_t ws_size,
                              hipStream_t stream) {
  const void* x    = d_in[0];
  const void* ei   = d_in[1];
  const void* W1   = d_in[2];
  const void* as1w = d_in[3];
  const void* ad1w = d_in[4];
  const void* b1   = d_in[5];
  const void* W2   = d_in[6];
  const void* as2w = d_in[7];
  const void* ad2w = d_in[8];
  const void* b2   = d_in[9];

  const int N  = out_size / 64;      // 50000
  const int F  = in_sizes[0] / N;    // 128
  const int E  = in_sizes[1] / 2;    // 800000
  const int H1 = in_sizes[3] / 64;   // 4
  const int D1 = H1 * 64;            // 256
  const int D2 = 64;                 // layer-2 output dim (H2 = 1)

  size_t off = 0;
  auto alloc = [&](size_t bytes) -> void* {
    void* p = (char*)d_ws + off;
    off += (bytes + 255) & ~(size_t)255;
    return p;
  };
  int* flags = (int*)alloc(2 * sizeof(int));
  __hip_bfloat16* h1 = (__hip_bfloat16*)alloc((size_t)N * D1 * 2);
  __hip_bfloat16* x2 = (__hip_bfloat16*)alloc((size_t)N * D1 * 2);
  __hip_bfloat16* h2 = h1;  // h1 dead after layer-1 aggregate; reuse
  unsigned short* xb  = (unsigned short*)alloc((size_t)N * F * 2);   // x in bf16
  unsigned short* w1t = (unsigned short*)alloc((size_t)D1 * F * 2);  // [256][128]
  unsigned short* w2t = (unsigned short*)alloc((size_t)D2 * D1 * 2); // [64][256]
  float* as1 = (float*)alloc((size_t)N * H1 * 4);
  float* ad1 = (float*)alloc((size_t)N * H1 * 4);
  float* wself1 = (float*)alloc((size_t)N * H1 * 4);
  float* den1 = (float*)alloc((size_t)N * H1 * 4);
  float* as2 = (float*)alloc((size_t)N * 4);
  float* ad2 = (float*)alloc((size_t)N * 4);
  float* wself2 = (float*)alloc((size_t)N * 4);
  float* den2 = (float*)alloc((size_t)N * 4);
  int* zero_region = (int*)alloc((size_t)2 * N * 4);  // deg | cursor
  int* deg = zero_region;
  int* cursor = zero_region + N;
  int* row_start = (int*)alloc((size_t)(N + 1) * 4);
  int* col_src = (int*)alloc((size_t)E * 4);
  float* wbuf = (float*)alloc((size_t)E * 4 * 4);  // L1: [E]float4; L2 reuses [E]float
  int* bsum = (int*)alloc((size_t)256 * 4);
  (void)ws_size; (void)n_in;

  const int nb = (N + 255) / 256;
  const int eb = (E + 255) / 256;
  const int db = (N + 3) / 4;
  const int gb = (N + 63) / 64;

  // ---- dtype detection + CSR build + GEMM prep (single prep dispatch)
  detect_kernel<<<1, 64, 0, stream>>>((const uint32_t*)x, (const uint32_t*)ei, flags);
  hipMemsetAsync(zero_region, 0, (size_t)2 * N * 4, stream);
  hist_kernel<<<eb, 256, 0, stream>>>(ei, E, deg, flags);
  scan_block_sums<<<nb, 256, 0, stream>>>(deg, bsum, N);
  scan_bsums<<<1, 256, 0, stream>>>(bsum, nb);
  scan_finalize<<<nb, 256, 0, stream>>>(deg, bsum, row_start, N);
  scatter_edges<<<eb, 256, 0, stream>>>(ei, E, row_start, cursor, col_src, flags);

  const size_t nx = (size_t)N * F;
  const int nb_cast = (int)((nx / 4 + 255) / 256);
  const int nb_t1 = (F * D1 + 255) / 256;
  const int nb_t2 = (D1 * D2 + 255) / 256;
  prep_all<<<nb_cast + nb_t1 + nb_t2, 256, 0, stream>>>(
      x, xb, nx, W1, w1t, F, D1, W2, w2t, D1, D2, nb_cast, nb_t1, flags);

  // ---- layer 1: GEMM (64x256 tile) + fused att dots
  gemm_mfma_att<16, 4><<<gb, 256, 0, stream>>>(
      xb, w1t, (unsigned short*)h1, as1w, ad1w, as1, ad1, wself1, N, F, flags);
  softmax_den4<<<db, 256, 0, stream>>>((const float4*)as1, (const float4*)ad1,
                                       row_start, col_src, (const float4*)wself1,
                                       (float4*)wbuf, (float4*)den1, N);
  aggregate4<<<db, 256, 0, stream>>>((const unsigned short*)h1, wself1, den1, wbuf,
                                     row_start, col_src, b1,
                                     (unsigned short*)x2, N, flags);

  // ---- layer 2: GEMM (64x64 tile) + fused att dots
  gemm_mfma_att<4, 1><<<gb, 256, 0, stream>>>(
      (const unsigned short*)x2, w2t, (unsigned short*)h2, as2w, ad2w,
      as2, ad2, wself2, N, D1, flags);
  softmax_den1<<<db, 256, 0, stream>>>(as2, ad2, row_start, col_src, wself2,
                                       wbuf, den2, N);
  aggregate1<<<db, 256, 0, stream>>>((const unsigned short*)h2, wself2, den2, wbuf,
                                     row_start, col_src, b2, d_out, N, flags);
}

// Round 12
// 383.822 us; speedup vs baseline: 1.0482x; 1.0350x over previous
//
#include <hip/hip_runtime.h>
#include <hip/hip_bf16.h>
#include <stdint.h>

// ---------------------------------------------------------------------------
// 2-layer GAT (inference) on MI355X, dtype-adaptive.
// Round-12 changes vs round-11 (397 us; top dispatch = layer-1 GEMM 74 us,
// MfmaUtil 1.6%, Occupancy 24% -> latency-bound, grid-starved):
//  * gemm_mfma_att templated on K (compile-time full unroll of the K-loop ->
//    cross-K ILP) and on NT/HB; layer-1 tile 64x256 -> 64x128 with grid.y=2
//    (2x blocks: 1564 -> ~6 blocks/CU; acc VGPRs 64 -> 32).
//  * __launch_bounds__(256, 4) caps VGPR at 128 (no unroll-induced spill).
// Everything else byte-identical to round 11.
// ---------------------------------------------------------------------------

typedef __attribute__((ext_vector_type(8))) short bf16x8;
typedef __attribute__((ext_vector_type(4))) float f32x4;

__device__ __forceinline__ float bf2f(__hip_bfloat16 v) { return __bfloat162float(v); }
__device__ __forceinline__ float bfbits2f(unsigned short s) {
  union { uint32_t u; float f; } v; v.u = ((uint32_t)s) << 16; return v.f;
}
__device__ __forceinline__ unsigned short f2bfbits(float f) {
  union { float f; uint32_t u; } v; v.f = f;
  uint32_t u = v.u;
  return (unsigned short)((u + 0x7fffu + ((u >> 16) & 1u)) >> 16);  // RNE
}

template <bool BF>
__device__ __forceinline__ float loadF(const void* p, size_t i) {
  if (BF) return bf2f(((const __hip_bfloat16*)p)[i]);
  return ((const float*)p)[i];
}
template <bool BF>
__device__ __forceinline__ void storeF(void* p, size_t i, float v) {
  if (BF) ((__hip_bfloat16*)p)[i] = __float2bfloat16(v);
  else    ((float*)p)[i] = v;
}
template <bool I64>
__device__ __forceinline__ int loadI(const void* p, size_t i) {
  if (I64) return (int)((const long long*)p)[i];
  return ((const int*)p)[i];
}
__device__ __forceinline__ float lrelu(float v) { return fmaxf(v, 0.2f * v); }

// ----------------- dtype detection (1 thread) ------------------------------
__global__ void detect_kernel(const uint32_t* __restrict__ xbits,
                              const uint32_t* __restrict__ eibits,
                              int* __restrict__ flags) {
  if (threadIdx.x != 0 || blockIdx.x != 0) return;
  int plausible = 0;
  for (int i = 0; i < 64; i++) {
    uint32_t u = xbits[i];
    uint32_t e = (u >> 23) & 0xffu;
    if ((e < 160u && e > 90u) || (u & 0x7fffffffu) == 0u) plausible++;
  }
  flags[0] = (plausible < 32) ? 1 : 0;  // 1 = floats are bf16
  int allz = 1;
  for (int i = 0; i < 64; i++)
    if (eibits[2 * i + 1] != 0u) allz = 0;
  flags[1] = allz;                      // 1 = edge_index is int64
}

// ----------------- prep (single dispatch): cast x; transpose W1, W2 --------
__global__ __launch_bounds__(256) void prep_all(
    const void* __restrict__ x, unsigned short* __restrict__ xb, size_t nx,
    const void* __restrict__ W1, unsigned short* __restrict__ w1t, int K1, int N1,
    const void* __restrict__ W2, unsigned short* __restrict__ w2t, int K2, int N2,
    int nb_cast, int nb_t1, const int* __restrict__ flags) {
  const int b = blockIdx.x;
  const bool f = flags[0] != 0;
  if (b < nb_cast) {
    size_t i = ((size_t)b * 256 + threadIdx.x) * 4;
    if (i >= nx) return;
    ushort4 o;
    if (f) {
      o = *(const ushort4*)((const unsigned short*)x + i);
    } else {
      float4 v = *(const float4*)((const float*)x + i);
      o.x = f2bfbits(v.x); o.y = f2bfbits(v.y);
      o.z = f2bfbits(v.z); o.w = f2bfbits(v.w);
    }
    *(ushort4*)(xb + i) = o;
  } else if (b < nb_cast + nb_t1) {
    int idx = (b - nb_cast) * 256 + threadIdx.x;
    if (idx >= K1 * N1) return;
    int k = idx / N1, n = idx - k * N1;
    float v = f ? loadF<true>(W1, idx) : loadF<false>(W1, idx);
    w1t[(size_t)n * K1 + k] = f2bfbits(v);
  } else {
    int idx = (b - nb_cast - nb_t1) * 256 + threadIdx.x;
    if (idx >= K2 * N2) return;
    int k = idx / N2, n = idx - k * N2;
    float v = f ? loadF<true>(W2, idx) : loadF<false>(W2, idx);
    w2t[(size_t)n * K2 + k] = f2bfbits(v);
  }
}

// ----------------- MFMA GEMM + fused attention-dot epilogue ----------------
// KC compile-time -> K-loop fully unrolled (cross-K ILP). Block = 4 waves,
// covers 64 rows x NT*16 cols at n0 = blockIdx.y*NT*16. HB heads per block
// (NT*16 = HB*64); global head = blockIdx.y*HB + h. Htot = total heads.
template <int KC, int NT, int HB>
__global__ __launch_bounds__(256, 4) void gemm_mfma_att(
    const unsigned short* __restrict__ A,   // [M][KC] bf16 bits
    const unsigned short* __restrict__ BT,  // [Htot*64][KC] bf16 bits
    unsigned short* __restrict__ C,         // [M][Htot*64] bf16 bits
    const void* __restrict__ att_s, const void* __restrict__ att_d,
    float* __restrict__ as_o, float* __restrict__ ad_o,
    float* __restrict__ wself_o,
    int M, int Htot, const int* __restrict__ flags) {
  const int lane = threadIdx.x & 63;
  const int col = lane & 15;
  const int quad = lane >> 4;
  const int m0 = blockIdx.x * 64 + (threadIdx.x >> 6) * 16;
  const int n0 = blockIdx.y * (NT * 16);
  const int NCOL = Htot * 64;

  int gm = m0 + col;                 // A row this lane supplies
  if (gm > M - 1) gm = M - 1;        // clamp: garbage only affects guarded rows
  const unsigned short* arow = A + (size_t)gm * KC + quad * 8;
  const unsigned short* bbase = BT + (size_t)(n0 + col) * KC + quad * 8;

  f32x4 acc[NT] = {};
#pragma unroll
  for (int k0 = 0; k0 < KC; k0 += 32) {
    bf16x8 a = *(const bf16x8*)(arow + k0);
#pragma unroll
    for (int s = 0; s < NT; s++) {
      bf16x8 b = *(const bf16x8*)(bbase + (size_t)s * 16 * KC + k0);
      acc[s] = __builtin_amdgcn_mfma_f32_16x16x32_bf16(a, b, acc[s], 0, 0, 0);
    }
  }
  // store C
#pragma unroll
  for (int s = 0; s < NT; s++)
#pragma unroll
    for (int r = 0; r < 4; r++) {
      int m = m0 + quad * 4 + r;
      if (m < M) C[(size_t)m * NCOL + n0 + s * 16 + col] = f2bfbits(acc[s][r]);
    }
  // fused attention dots: head h covers s in [h*SC, (h+1)*SC)
  const int SC = NT / HB;
  const bool f = flags[0] != 0;
#pragma unroll
  for (int h = 0; h < HB; h++) {
    const int gh = blockIdx.y * HB + h;
    float ps[4] = {0.f, 0.f, 0.f, 0.f};
    float pd[4] = {0.f, 0.f, 0.f, 0.f};
#pragma unroll
    for (int j = 0; j < SC; j++) {
      int s = h * SC + j;
      int ci = gh * 64 + j * 16 + col;
      float av = f ? loadF<true>(att_s, ci) : loadF<false>(att_s, ci);
      float dv = f ? loadF<true>(att_d, ci) : loadF<false>(att_d, ci);
#pragma unroll
      for (int r = 0; r < 4; r++) {
        ps[r] += acc[s][r] * av;
        pd[r] += acc[s][r] * dv;
      }
    }
#pragma unroll
    for (int o = 1; o < 16; o <<= 1) {
#pragma unroll
      for (int r = 0; r < 4; r++) {
        ps[r] += __shfl_xor(ps[r], o);
        pd[r] += __shfl_xor(pd[r], o);
      }
    }
    if (col == 0) {
#pragma unroll
      for (int r = 0; r < 4; r++) {
        int m = m0 + quad * 4 + r;
        if (m < M) {
          as_o[m * Htot + gh] = ps[r];
          ad_o[m * Htot + gh] = pd[r];
          wself_o[m * Htot + gh] = __expf(lrelu(ps[r] + pd[r]));  // no max-sub
        }
      }
    }
  }
}

// ----------------- CSR build ------------------------------------------------
__global__ void hist_kernel(const void* __restrict__ ei, int E,
                            int* __restrict__ deg, const int* __restrict__ flags) {
  int e = blockIdx.x * blockDim.x + threadIdx.x;
  if (e >= E) return;
  int d = flags[1] ? loadI<true>(ei, (size_t)E + e) : loadI<false>(ei, (size_t)E + e);
  atomicAdd(&deg[d], 1);
}

__global__ __launch_bounds__(256) void scan_block_sums(const int* __restrict__ deg,
                                                       int* __restrict__ bsum, int n) {
  __shared__ int buf[256];
  const int t = threadIdx.x;
  const int i = blockIdx.x * 256 + t;
  buf[t] = (i < n) ? deg[i] : 0;
  __syncthreads();
  for (int o = 128; o > 0; o >>= 1) {
    if (t < o) buf[t] += buf[t + o];
    __syncthreads();
  }
  if (t == 0) bsum[blockIdx.x] = buf[0];
}

__global__ __launch_bounds__(256) void scan_bsums(int* __restrict__ bsum, int nb) {
  __shared__ int buf[256];
  const int t = threadIdx.x;
  int orig = (t < nb) ? bsum[t] : 0;
  buf[t] = orig;
  __syncthreads();
  for (int o = 1; o < 256; o <<= 1) {
    int v = (t >= o) ? buf[t - o] : 0;
    __syncthreads();
    buf[t] += v;
    __syncthreads();
  }
  if (t < nb) bsum[t] = buf[t] - orig;  // exclusive
}

__global__ __launch_bounds__(256) void scan_finalize(const int* __restrict__ deg,
                                                     const int* __restrict__ bsum,
                                                     int* __restrict__ row_start, int n) {
  __shared__ int buf[256];
  const int t = threadIdx.x;
  const int i = blockIdx.x * 256 + t;
  int v = (i < n) ? deg[i] : 0;
  buf[t] = v;
  __syncthreads();
  for (int o = 1; o < 256; o <<= 1) {
    int x = (t >= o) ? buf[t - o] : 0;
    __syncthreads();
    buf[t] += x;
    __syncthreads();
  }
  if (i < n) row_start[i + 1] = bsum[blockIdx.x] + buf[t];
  if (i == 0) row_start[0] = 0;
}

__global__ void scatter_edges(const void* __restrict__ ei, int E,
                              const int* __restrict__ row_start,
                              int* __restrict__ cursor, int* __restrict__ col_src,
                              const int* __restrict__ flags) {
  int e = blockIdx.x * blockDim.x + threadIdx.x;
  if (e >= E) return;
  int s, d;
  if (flags[1]) { s = loadI<true>(ei, e);  d = loadI<true>(ei, (size_t)E + e); }
  else          { s = loadI<false>(ei, e); d = loadI<false>(ei, (size_t)E + e); }
  int pos = atomicAdd(&cursor[d], 1);
  col_src[row_start[d] + pos] = s;
}

// ----------------- per-dst softmax denominator (single sweep, no max) ------
__global__ __launch_bounds__(256) void softmax_den4(
    const float4* __restrict__ as4, const float4* __restrict__ ad4,
    const int* __restrict__ row_start, const int* __restrict__ col_src,
    const float4* __restrict__ wself4,
    float4* __restrict__ wbuf, float4* __restrict__ den4, int N) {
  const int dst = blockIdx.x * 4 + (threadIdx.x >> 6);
  if (dst >= N) return;
  const int l = threadIdx.x & 63;
  const int rs = row_start[dst];
  const int dg = row_start[dst + 1] - rs;
  const float4 adv = ad4[dst];

  float p0 = 0.f, p1 = 0.f, p2 = 0.f, p3 = 0.f;
  for (int base = 0; base < dg; base += 64) {
    int i = base + l;
    if (i < dg) {
      float4 a = as4[col_src[rs + i]];
      float4 w;
      w.x = __expf(lrelu(a.x + adv.x));
      w.y = __expf(lrelu(a.y + adv.y));
      w.z = __expf(lrelu(a.z + adv.z));
      w.w = __expf(lrelu(a.w + adv.w));
      wbuf[rs + i] = w;
      p0 += w.x; p1 += w.y; p2 += w.z; p3 += w.w;
    }
  }
#pragma unroll
  for (int o = 32; o > 0; o >>= 1) {
    p0 += __shfl_xor(p0, o);
    p1 += __shfl_xor(p1, o);
    p2 += __shfl_xor(p2, o);
    p3 += __shfl_xor(p3, o);
  }
  if (l == 0) {
    float4 ws = wself4[dst];
    float4 dn;
    dn.x = p0 + ws.x; dn.y = p1 + ws.y; dn.z = p2 + ws.z; dn.w = p3 + ws.w;
    den4[dst] = dn;
  }
}

__global__ __launch_bounds__(256) void softmax_den1(
    const float* __restrict__ as_, const float* __restrict__ ad_,
    const int* __restrict__ row_start, const int* __restrict__ col_src,
    const float* __restrict__ wself,
    float* __restrict__ wbuf, float* __restrict__ den, int N) {
  const int dst = blockIdx.x * 4 + (threadIdx.x >> 6);
  if (dst >= N) return;
  const int l = threadIdx.x & 63;
  const int rs = row_start[dst];
  const int dg = row_start[dst + 1] - rs;
  const float adv = ad_[dst];

  float p = 0.f;
  for (int base = 0; base < dg; base += 64) {
    int i = base + l;
    if (i < dg) {
      float w = __expf(lrelu(as_[col_src[rs + i]] + adv));
      wbuf[rs + i] = w;
      p += w;
    }
  }
#pragma unroll
  for (int o = 32; o > 0; o >>= 1) p += __shfl_xor(p, o);
  if (l == 0) den[dst] = p + wself[dst];
}

// ----------------- aggregation: pure weighted gather -----------------------
__global__ __launch_bounds__(256) void aggregate4(
    const unsigned short* __restrict__ h_in,   // [N][256] bf16 bits
    const float* __restrict__ wselfA, const float* __restrict__ denA,
    const float* __restrict__ wbuf,            // [E][4]
    const int* __restrict__ row_start, const int* __restrict__ col_src,
    const void* __restrict__ bias,
    unsigned short* __restrict__ out,          // [N][256] bf16 bits (x2)
    int N, const int* __restrict__ flags) {
  const int dst = blockIdx.x * 4 + (threadIdx.x >> 6);
  if (dst >= N) return;
  const int l = threadIdx.x & 63;
  const int h = l >> 4;
  const int rs = row_start[dst];
  const int dg = row_start[dst + 1] - rs;
  const float ws = wselfA[dst * 4 + h];
  const float inv = 1.0f / (denA[dst * 4 + h] + 1e-16f);

  float a0, a1, a2, a3;
  {
    ushort4 sv = *(const ushort4*)(h_in + (size_t)dst * 256 + 4 * l);
    a0 = ws * bfbits2f(sv.x);
    a1 = ws * bfbits2f(sv.y);
    a2 = ws * bfbits2f(sv.z);
    a3 = ws * bfbits2f(sv.w);
  }
#pragma unroll 8
  for (int i = 0; i < dg; i++) {
    int sn = col_src[rs + i];
    float w = wbuf[(size_t)(rs + i) * 4 + h];
    ushort4 sv = *(const ushort4*)(h_in + (size_t)sn * 256 + 4 * l);
    a0 += w * bfbits2f(sv.x);
    a1 += w * bfbits2f(sv.y);
    a2 += w * bfbits2f(sv.z);
    a3 += w * bfbits2f(sv.w);
  }
  const bool f = flags[0] != 0;
  float b0, b1, b2, b3;
  if (f) {
    b0 = loadF<true>(bias, 4 * l + 0); b1 = loadF<true>(bias, 4 * l + 1);
    b2 = loadF<true>(bias, 4 * l + 2); b3 = loadF<true>(bias, 4 * l + 3);
  } else {
    b0 = loadF<false>(bias, 4 * l + 0); b1 = loadF<false>(bias, 4 * l + 1);
    b2 = loadF<false>(bias, 4 * l + 2); b3 = loadF<false>(bias, 4 * l + 3);
  }
  float o0 = a0 * inv + b0, o1 = a1 * inv + b1;
  float o2 = a2 * inv + b2, o3 = a3 * inv + b3;
  o0 = o0 > 0.f ? o0 : __expf(o0) - 1.f;
  o1 = o1 > 0.f ? o1 : __expf(o1) - 1.f;
  o2 = o2 > 0.f ? o2 : __expf(o2) - 1.f;
  o3 = o3 > 0.f ? o3 : __expf(o3) - 1.f;
  ushort4 ov;
  ov.x = f2bfbits(o0); ov.y = f2bfbits(o1); ov.z = f2bfbits(o2); ov.w = f2bfbits(o3);
  *(ushort4*)(out + (size_t)dst * 256 + 4 * l) = ov;
}

__global__ __launch_bounds__(256) void aggregate1(
    const unsigned short* __restrict__ h_in,   // [N][64] bf16 bits
    const float* __restrict__ wselfA, const float* __restrict__ denA,
    const float* __restrict__ wbuf,            // [E]
    const int* __restrict__ row_start, const int* __restrict__ col_src,
    const void* __restrict__ bias,
    void* __restrict__ out, int N, const int* __restrict__ flags) {
  const int dst = blockIdx.x * 4 + (threadIdx.x >> 6);
  if (dst >= N) return;
  const int l = threadIdx.x & 63;
  const int rs = row_start[dst];
  const int dg = row_start[dst + 1] - rs;
  const float ws = wselfA[dst];
  const float inv = 1.0f / (denA[dst] + 1e-16f);

  float acc = ws * bfbits2f(h_in[(size_t)dst * 64 + l]);
#pragma unroll 8
  for (int i = 0; i < dg; i++) {
    int sn = col_src[rs + i];
    float w = wbuf[rs + i];
    acc += w * bfbits2f(h_in[(size_t)sn * 64 + l]);
  }
  const bool f = flags[0] != 0;
  float bv = f ? loadF<true>(bias, l) : loadF<false>(bias, l);
  float o = acc * inv + bv;
  size_t oi = (size_t)dst * 64 + l;
  if (f) storeF<true>(out, oi, o);
  else   storeF<false>(out, oi, o);
}

// ---------------------------------------------------------------------------
extern "C" void kernel_launch(void* const* d_in, const int* in_sizes, int n_in,
                              void* d_out, int out_size, void* d_ws, size_t ws_size,
                              hipStream_t stream) {
  const void* x    = d_in[0];
  const void* ei   = d_in[1];
  const void* W1   = d_in[2];
  const void* as1w = d_in[3];
  const void* ad1w = d_in[4];
  const void* b1   = d_in[5];
  const void* W2   = d_in[6];
  const void* as2w = d_in[7];
  const void* ad2w = d_in[8];
  const void* b2   = d_in[9];

  const int N  = out_size / 64;      // 50000
  const int F  = in_sizes[0] / N;    // 128
  const int E  = in_sizes[1] / 2;    // 800000
  const int H1 = in_sizes[3] / 64;   // 4
  const int D1 = H1 * 64;            // 256
  const int D2 = 64;                 // layer-2 output dim (H2 = 1)

  size_t off = 0;
  auto alloc = [&](size_t bytes) -> void* {
    void* p = (char*)d_ws + off;
    off += (bytes + 255) & ~(size_t)255;
    return p;
  };
  int* flags = (int*)alloc(2 * sizeof(int));
  __hip_bfloat16* h1 = (__hip_bfloat16*)alloc((size_t)N * D1 * 2);
  __hip_bfloat16* x2 = (__hip_bfloat16*)alloc((size_t)N * D1 * 2);
  __hip_bfloat16* h2 = h1;  // h1 dead after layer-1 aggregate; reuse
  unsigned short* xb  = (unsigned short*)alloc((size_t)N * F * 2);   // x in bf16
  unsigned short* w1t = (unsigned short*)alloc((size_t)D1 * F * 2);  // [256][128]
  unsigned short* w2t = (unsigned short*)alloc((size_t)D2 * D1 * 2); // [64][256]
  float* as1 = (float*)alloc((size_t)N * H1 * 4);
  float* ad1 = (float*)alloc((size_t)N * H1 * 4);
  float* wself1 = (float*)alloc((size_t)N * H1 * 4);
  float* den1 = (float*)alloc((size_t)N * H1 * 4);
  float* as2 = (float*)alloc((size_t)N * 4);
  float* ad2 = (float*)alloc((size_t)N * 4);
  float* wself2 = (float*)alloc((size_t)N * 4);
  float* den2 = (float*)alloc((size_t)N * 4);
  int* zero_region = (int*)alloc((size_t)2 * N * 4);  // deg | cursor
  int* deg = zero_region;
  int* cursor = zero_region + N;
  int* row_start = (int*)alloc((size_t)(N + 1) * 4);
  int* col_src = (int*)alloc((size_t)E * 4);
  float* wbuf = (float*)alloc((size_t)E * 4 * 4);  // L1: [E]float4; L2 reuses [E]float
  int* bsum = (int*)alloc((size_t)256 * 4);
  (void)ws_size; (void)n_in;

  const int nb = (N + 255) / 256;
  const int eb = (E + 255) / 256;
  const int db = (N + 3) / 4;
  const int gb = (N + 63) / 64;

  // ---- dtype detection + CSR build + GEMM prep (single prep dispatch)
  detect_kernel<<<1, 64, 0, stream>>>((const uint32_t*)x, (const uint32_t*)ei, flags);
  hipMemsetAsync(zero_region, 0, (size_t)2 * N * 4, stream);
  hist_kernel<<<eb, 256, 0, stream>>>(ei, E, deg, flags);
  scan_block_sums<<<nb, 256, 0, stream>>>(deg, bsum, N);
  scan_bsums<<<1, 256, 0, stream>>>(bsum, nb);
  scan_finalize<<<nb, 256, 0, stream>>>(deg, bsum, row_start, N);
  scatter_edges<<<eb, 256, 0, stream>>>(ei, E, row_start, cursor, col_src, flags);

  const size_t nx = (size_t)N * F;
  const int nb_cast = (int)((nx / 4 + 255) / 256);
  const int nb_t1 = (F * D1 + 255) / 256;
  const int nb_t2 = (D1 * D2 + 255) / 256;
  prep_all<<<nb_cast + nb_t1 + nb_t2, 256, 0, stream>>>(
      x, xb, nx, W1, w1t, F, D1, W2, w2t, D1, D2, nb_cast, nb_t1, flags);

  // ---- layer 1: GEMM 64x128 tiles (grid.y = 2), K=128 unrolled
  gemm_mfma_att<128, 8, 2><<<dim3(gb, 2), 256, 0, stream>>>(
      xb, w1t, (unsigned short*)h1, as1w, ad1w, as1, ad1, wself1, N, H1, flags);
  softmax_den4<<<db, 256, 0, stream>>>((const float4*)as1, (const float4*)ad1,
                                       row_start, col_src, (const float4*)wself1,
                                       (float4*)wbuf, (float4*)den1, N);
  aggregate4<<<db, 256, 0, stream>>>((const unsigned short*)h1, wself1, den1, wbuf,
                                     row_start, col_src, b1,
                                     (unsigned short*)x2, N, flags);

  // ---- layer 2: GEMM 64x64 tile, K=256 unrolled
  gemm_mfma_att<256, 4, 1><<<dim3(gb, 1), 256, 0, stream>>>(
      (const unsigned short*)x2, w2t, (unsigned short*)h2, as2w, ad2w,
      as2, ad2, wself2, N, 1, flags);
  softmax_den1<<<db, 256, 0, stream>>>(as2, ad2, row_start, col_src, wself2,
                                       wbuf, den2, N);
  aggregate1<<<db, 256, 0, stream>>>((const unsigned short*)h2, wself2, den2, wbuf,
                                     row_start, col_src, b2, d_out, N, flags);
}

// Round 13
// 369.561 us; speedup vs baseline: 1.0887x; 1.0386x over previous
//
#include <hip/hip_runtime.h>
#include <hip/hip_bf16.h>
#include <stdint.h>

// ---------------------------------------------------------------------------
// 2-layer GAT (inference) on MI355X, dtype-adaptive.
// Round-13 changes vs round-12 (383.8 us):
//  * aggregate4 reverted to round-9 body (unroll 4, VGPR 24): round-12's
//    unroll-8 raised VGPR 24->36, occupancy 68->60%, dur 63->71 us.
//  * aggregate1 restructured: lane = (slot=l>>4, el=l&15), ushort4 row loads,
//    4 edges in flight, slot partials reduced via shfl_xor(16/32) (epilogue
//    pattern proven in round 5). Weights still stream from wbuf.
// Everything else byte-identical to round 12.
// ---------------------------------------------------------------------------

typedef __attribute__((ext_vector_type(8))) short bf16x8;
typedef __attribute__((ext_vector_type(4))) float f32x4;

__device__ __forceinline__ float bf2f(__hip_bfloat16 v) { return __bfloat162float(v); }
__device__ __forceinline__ float bfbits2f(unsigned short s) {
  union { uint32_t u; float f; } v; v.u = ((uint32_t)s) << 16; return v.f;
}
__device__ __forceinline__ unsigned short f2bfbits(float f) {
  union { float f; uint32_t u; } v; v.f = f;
  uint32_t u = v.u;
  return (unsigned short)((u + 0x7fffu + ((u >> 16) & 1u)) >> 16);  // RNE
}

template <bool BF>
__device__ __forceinline__ float loadF(const void* p, size_t i) {
  if (BF) return bf2f(((const __hip_bfloat16*)p)[i]);
  return ((const float*)p)[i];
}
template <bool BF>
__device__ __forceinline__ void storeF(void* p, size_t i, float v) {
  if (BF) ((__hip_bfloat16*)p)[i] = __float2bfloat16(v);
  else    ((float*)p)[i] = v;
}
template <bool I64>
__device__ __forceinline__ int loadI(const void* p, size_t i) {
  if (I64) return (int)((const long long*)p)[i];
  return ((const int*)p)[i];
}
__device__ __forceinline__ float lrelu(float v) { return fmaxf(v, 0.2f * v); }

// ----------------- dtype detection (1 thread) ------------------------------
__global__ void detect_kernel(const uint32_t* __restrict__ xbits,
                              const uint32_t* __restrict__ eibits,
                              int* __restrict__ flags) {
  if (threadIdx.x != 0 || blockIdx.x != 0) return;
  int plausible = 0;
  for (int i = 0; i < 64; i++) {
    uint32_t u = xbits[i];
    uint32_t e = (u >> 23) & 0xffu;
    if ((e < 160u && e > 90u) || (u & 0x7fffffffu) == 0u) plausible++;
  }
  flags[0] = (plausible < 32) ? 1 : 0;  // 1 = floats are bf16
  int allz = 1;
  for (int i = 0; i < 64; i++)
    if (eibits[2 * i + 1] != 0u) allz = 0;
  flags[1] = allz;                      // 1 = edge_index is int64
}

// ----------------- prep (single dispatch): cast x; transpose W1, W2 --------
__global__ __launch_bounds__(256) void prep_all(
    const void* __restrict__ x, unsigned short* __restrict__ xb, size_t nx,
    const void* __restrict__ W1, unsigned short* __restrict__ w1t, int K1, int N1,
    const void* __restrict__ W2, unsigned short* __restrict__ w2t, int K2, int N2,
    int nb_cast, int nb_t1, const int* __restrict__ flags) {
  const int b = blockIdx.x;
  const bool f = flags[0] != 0;
  if (b < nb_cast) {
    size_t i = ((size_t)b * 256 + threadIdx.x) * 4;
    if (i >= nx) return;
    ushort4 o;
    if (f) {
      o = *(const ushort4*)((const unsigned short*)x + i);
    } else {
      float4 v = *(const float4*)((const float*)x + i);
      o.x = f2bfbits(v.x); o.y = f2bfbits(v.y);
      o.z = f2bfbits(v.z); o.w = f2bfbits(v.w);
    }
    *(ushort4*)(xb + i) = o;
  } else if (b < nb_cast + nb_t1) {
    int idx = (b - nb_cast) * 256 + threadIdx.x;
    if (idx >= K1 * N1) return;
    int k = idx / N1, n = idx - k * N1;
    float v = f ? loadF<true>(W1, idx) : loadF<false>(W1, idx);
    w1t[(size_t)n * K1 + k] = f2bfbits(v);
  } else {
    int idx = (b - nb_cast - nb_t1) * 256 + threadIdx.x;
    if (idx >= K2 * N2) return;
    int k = idx / N2, n = idx - k * N2;
    float v = f ? loadF<true>(W2, idx) : loadF<false>(W2, idx);
    w2t[(size_t)n * K2 + k] = f2bfbits(v);
  }
}

// ----------------- MFMA GEMM + fused attention-dot epilogue ----------------
template <int KC, int NT, int HB>
__global__ __launch_bounds__(256, 4) void gemm_mfma_att(
    const unsigned short* __restrict__ A,   // [M][KC] bf16 bits
    const unsigned short* __restrict__ BT,  // [Htot*64][KC] bf16 bits
    unsigned short* __restrict__ C,         // [M][Htot*64] bf16 bits
    const void* __restrict__ att_s, const void* __restrict__ att_d,
    float* __restrict__ as_o, float* __restrict__ ad_o,
    float* __restrict__ wself_o,
    int M, int Htot, const int* __restrict__ flags) {
  const int lane = threadIdx.x & 63;
  const int col = lane & 15;
  const int quad = lane >> 4;
  const int m0 = blockIdx.x * 64 + (threadIdx.x >> 6) * 16;
  const int n0 = blockIdx.y * (NT * 16);
  const int NCOL = Htot * 64;

  int gm = m0 + col;                 // A row this lane supplies
  if (gm > M - 1) gm = M - 1;        // clamp: garbage only affects guarded rows
  const unsigned short* arow = A + (size_t)gm * KC + quad * 8;
  const unsigned short* bbase = BT + (size_t)(n0 + col) * KC + quad * 8;

  f32x4 acc[NT] = {};
#pragma unroll
  for (int k0 = 0; k0 < KC; k0 += 32) {
    bf16x8 a = *(const bf16x8*)(arow + k0);
#pragma unroll
    for (int s = 0; s < NT; s++) {
      bf16x8 b = *(const bf16x8*)(bbase + (size_t)s * 16 * KC + k0);
      acc[s] = __builtin_amdgcn_mfma_f32_16x16x32_bf16(a, b, acc[s], 0, 0, 0);
    }
  }
  // store C
#pragma unroll
  for (int s = 0; s < NT; s++)
#pragma unroll
    for (int r = 0; r < 4; r++) {
      int m = m0 + quad * 4 + r;
      if (m < M) C[(size_t)m * NCOL + n0 + s * 16 + col] = f2bfbits(acc[s][r]);
    }
  // fused attention dots: head h covers s in [h*SC, (h+1)*SC)
  const int SC = NT / HB;
  const bool f = flags[0] != 0;
#pragma unroll
  for (int h = 0; h < HB; h++) {
    const int gh = blockIdx.y * HB + h;
    float ps[4] = {0.f, 0.f, 0.f, 0.f};
    float pd[4] = {0.f, 0.f, 0.f, 0.f};
#pragma unroll
    for (int j = 0; j < SC; j++) {
      int s = h * SC + j;
      int ci = gh * 64 + j * 16 + col;
      float av = f ? loadF<true>(att_s, ci) : loadF<false>(att_s, ci);
      float dv = f ? loadF<true>(att_d, ci) : loadF<false>(att_d, ci);
#pragma unroll
      for (int r = 0; r < 4; r++) {
        ps[r] += acc[s][r] * av;
        pd[r] += acc[s][r] * dv;
      }
    }
#pragma unroll
    for (int o = 1; o < 16; o <<= 1) {
#pragma unroll
      for (int r = 0; r < 4; r++) {
        ps[r] += __shfl_xor(ps[r], o);
        pd[r] += __shfl_xor(pd[r], o);
      }
    }
    if (col == 0) {
#pragma unroll
      for (int r = 0; r < 4; r++) {
        int m = m0 + quad * 4 + r;
        if (m < M) {
          as_o[m * Htot + gh] = ps[r];
          ad_o[m * Htot + gh] = pd[r];
          wself_o[m * Htot + gh] = __expf(lrelu(ps[r] + pd[r]));  // no max-sub
        }
      }
    }
  }
}

// ----------------- CSR build ------------------------------------------------
__global__ void hist_kernel(const void* __restrict__ ei, int E,
                            int* __restrict__ deg, const int* __restrict__ flags) {
  int e = blockIdx.x * blockDim.x + threadIdx.x;
  if (e >= E) return;
  int d = flags[1] ? loadI<true>(ei, (size_t)E + e) : loadI<false>(ei, (size_t)E + e);
  atomicAdd(&deg[d], 1);
}

__global__ __launch_bounds__(256) void scan_block_sums(const int* __restrict__ deg,
                                                       int* __restrict__ bsum, int n) {
  __shared__ int buf[256];
  const int t = threadIdx.x;
  const int i = blockIdx.x * 256 + t;
  buf[t] = (i < n) ? deg[i] : 0;
  __syncthreads();
  for (int o = 128; o > 0; o >>= 1) {
    if (t < o) buf[t] += buf[t + o];
    __syncthreads();
  }
  if (t == 0) bsum[blockIdx.x] = buf[0];
}

__global__ __launch_bounds__(256) void scan_bsums(int* __restrict__ bsum, int nb) {
  __shared__ int buf[256];
  const int t = threadIdx.x;
  int orig = (t < nb) ? bsum[t] : 0;
  buf[t] = orig;
  __syncthreads();
  for (int o = 1; o < 256; o <<= 1) {
    int v = (t >= o) ? buf[t - o] : 0;
    __syncthreads();
    buf[t] += v;
    __syncthreads();
  }
  if (t < nb) bsum[t] = buf[t] - orig;  // exclusive
}

__global__ __launch_bounds__(256) void scan_finalize(const int* __restrict__ deg,
                                                     const int* __restrict__ bsum,
                                                     int* __restrict__ row_start, int n) {
  __shared__ int buf[256];
  const int t = threadIdx.x;
  const int i = blockIdx.x * 256 + t;
  int v = (i < n) ? deg[i] : 0;
  buf[t] = v;
  __syncthreads();
  for (int o = 1; o < 256; o <<= 1) {
    int x = (t >= o) ? buf[t - o] : 0;
    __syncthreads();
    buf[t] += x;
    __syncthreads();
  }
  if (i < n) row_start[i + 1] = bsum[blockIdx.x] + buf[t];
  if (i == 0) row_start[0] = 0;
}

__global__ void scatter_edges(const void* __restrict__ ei, int E,
                              const int* __restrict__ row_start,
                              int* __restrict__ cursor, int* __restrict__ col_src,
                              const int* __restrict__ flags) {
  int e = blockIdx.x * blockDim.x + threadIdx.x;
  if (e >= E) return;
  int s, d;
  if (flags[1]) { s = loadI<true>(ei, e);  d = loadI<true>(ei, (size_t)E + e); }
  else          { s = loadI<false>(ei, e); d = loadI<false>(ei, (size_t)E + e); }
  int pos = atomicAdd(&cursor[d], 1);
  col_src[row_start[d] + pos] = s;
}

// ----------------- per-dst softmax denominator (single sweep, no max) ------
__global__ __launch_bounds__(256) void softmax_den4(
    const float4* __restrict__ as4, const float4* __restrict__ ad4,
    const int* __restrict__ row_start, const int* __restrict__ col_src,
    const float4* __restrict__ wself4,
    float4* __restrict__ wbuf, float4* __restrict__ den4, int N) {
  const int dst = blockIdx.x * 4 + (threadIdx.x >> 6);
  if (dst >= N) return;
  const int l = threadIdx.x & 63;
  const int rs = row_start[dst];
  const int dg = row_start[dst + 1] - rs;
  const float4 adv = ad4[dst];

  float p0 = 0.f, p1 = 0.f, p2 = 0.f, p3 = 0.f;
  for (int base = 0; base < dg; base += 64) {
    int i = base + l;
    if (i < dg) {
      float4 a = as4[col_src[rs + i]];
      float4 w;
      w.x = __expf(lrelu(a.x + adv.x));
      w.y = __expf(lrelu(a.y + adv.y));
      w.z = __expf(lrelu(a.z + adv.z));
      w.w = __expf(lrelu(a.w + adv.w));
      wbuf[rs + i] = w;
      p0 += w.x; p1 += w.y; p2 += w.z; p3 += w.w;
    }
  }
#pragma unroll
  for (int o = 32; o > 0; o >>= 1) {
    p0 += __shfl_xor(p0, o);
    p1 += __shfl_xor(p1, o);
    p2 += __shfl_xor(p2, o);
    p3 += __shfl_xor(p3, o);
  }
  if (l == 0) {
    float4 ws = wself4[dst];
    float4 dn;
    dn.x = p0 + ws.x; dn.y = p1 + ws.y; dn.z = p2 + ws.z; dn.w = p3 + ws.w;
    den4[dst] = dn;
  }
}

__global__ __launch_bounds__(256) void softmax_den1(
    const float* __restrict__ as_, const float* __restrict__ ad_,
    const int* __restrict__ row_start, const int* __restrict__ col_src,
    const float* __restrict__ wself,
    float* __restrict__ wbuf, float* __restrict__ den, int N) {
  const int dst = blockIdx.x * 4 + (threadIdx.x >> 6);
  if (dst >= N) return;
  const int l = threadIdx.x & 63;
  const int rs = row_start[dst];
  const int dg = row_start[dst + 1] - rs;
  const float adv = ad_[dst];

  float p = 0.f;
  for (int base = 0; base < dg; base += 64) {
    int i = base + l;
    if (i < dg) {
      float w = __expf(lrelu(as_[col_src[rs + i]] + adv));
      wbuf[rs + i] = w;
      p += w;
    }
  }
#pragma unroll
  for (int o = 32; o > 0; o >>= 1) p += __shfl_xor(p, o);
  if (l == 0) den[dst] = p + wself[dst];
}

// ----------------- aggregation: pure weighted gather -----------------------
// H=4 (round-9 proven body: unroll 4, VGPR 24, ~68% occupancy)
__global__ __launch_bounds__(256) void aggregate4(
    const unsigned short* __restrict__ h_in,   // [N][256] bf16 bits
    const float* __restrict__ wselfA, const float* __restrict__ denA,
    const float* __restrict__ wbuf,            // [E][4]
    const int* __restrict__ row_start, const int* __restrict__ col_src,
    const void* __restrict__ bias,
    unsigned short* __restrict__ out,          // [N][256] bf16 bits (x2)
    int N, const int* __restrict__ flags) {
  const int dst = blockIdx.x * 4 + (threadIdx.x >> 6);
  if (dst >= N) return;
  const int l = threadIdx.x & 63;
  const int h = l >> 4;
  const int rs = row_start[dst];
  const int dg = row_start[dst + 1] - rs;
  const float ws = wselfA[dst * 4 + h];
  const float inv = 1.0f / (denA[dst * 4 + h] + 1e-16f);

  float a0, a1, a2, a3;
  {
    ushort4 sv = *(const ushort4*)(h_in + (size_t)dst * 256 + 4 * l);
    a0 = ws * bfbits2f(sv.x);
    a1 = ws * bfbits2f(sv.y);
    a2 = ws * bfbits2f(sv.z);
    a3 = ws * bfbits2f(sv.w);
  }
#pragma unroll 4
  for (int i = 0; i < dg; i++) {
    int sn = col_src[rs + i];
    float w = wbuf[(size_t)(rs + i) * 4 + h];
    ushort4 sv = *(const ushort4*)(h_in + (size_t)sn * 256 + 4 * l);
    a0 += w * bfbits2f(sv.x);
    a1 += w * bfbits2f(sv.y);
    a2 += w * bfbits2f(sv.z);
    a3 += w * bfbits2f(sv.w);
  }
  const bool f = flags[0] != 0;
  float b0, b1, b2, b3;
  if (f) {
    b0 = loadF<true>(bias, 4 * l + 0); b1 = loadF<true>(bias, 4 * l + 1);
    b2 = loadF<true>(bias, 4 * l + 2); b3 = loadF<true>(bias, 4 * l + 3);
  } else {
    b0 = loadF<false>(bias, 4 * l + 0); b1 = loadF<false>(bias, 4 * l + 1);
    b2 = loadF<false>(bias, 4 * l + 2); b3 = loadF<false>(bias, 4 * l + 3);
  }
  float o0 = a0 * inv + b0, o1 = a1 * inv + b1;
  float o2 = a2 * inv + b2, o3 = a3 * inv + b3;
  o0 = o0 > 0.f ? o0 : __expf(o0) - 1.f;
  o1 = o1 > 0.f ? o1 : __expf(o1) - 1.f;
  o2 = o2 > 0.f ? o2 : __expf(o2) - 1.f;
  o3 = o3 > 0.f ? o3 : __expf(o3) - 1.f;
  ushort4 ov;
  ov.x = f2bfbits(o0); ov.y = f2bfbits(o1); ov.z = f2bfbits(o2); ov.w = f2bfbits(o3);
  *(ushort4*)(out + (size_t)dst * 256 + 4 * l) = ov;
}

// H=1: lane = (slot = l>>4, el = l&15); lane covers channels 4el..4el+3;
// 4 edges in flight (slots); slot partials reduced via shfl_xor(16/32).
__global__ __launch_bounds__(256) void aggregate1(
    const unsigned short* __restrict__ h_in,   // [N][64] bf16 bits
    const float* __restrict__ wselfA, const float* __restrict__ denA,
    const float* __restrict__ wbuf,            // [E]
    const int* __restrict__ row_start, const int* __restrict__ col_src,
    const void* __restrict__ bias,
    void* __restrict__ out, int N, const int* __restrict__ flags) {
  const int dst = blockIdx.x * 4 + (threadIdx.x >> 6);
  if (dst >= N) return;
  const int l = threadIdx.x & 63;
  const int el = l & 15;
  const int slot = l >> 4;
  const int rs = row_start[dst];
  const int dg = row_start[dst + 1] - rs;
  const float ws = wselfA[dst];

  float a0 = 0.f, a1 = 0.f, a2 = 0.f, a3 = 0.f;
  if (slot == 0) {
    ushort4 sv = *(const ushort4*)(h_in + (size_t)dst * 64 + 4 * el);
    a0 = ws * bfbits2f(sv.x);
    a1 = ws * bfbits2f(sv.y);
    a2 = ws * bfbits2f(sv.z);
    a3 = ws * bfbits2f(sv.w);
  }
#pragma unroll 2
  for (int i = slot; i < dg; i += 4) {
    int sn = col_src[rs + i];
    float w = wbuf[rs + i];
    ushort4 sv = *(const ushort4*)(h_in + (size_t)sn * 64 + 4 * el);
    a0 += w * bfbits2f(sv.x);
    a1 += w * bfbits2f(sv.y);
    a2 += w * bfbits2f(sv.z);
    a3 += w * bfbits2f(sv.w);
  }
  a0 += __shfl_xor(a0, 16); a0 += __shfl_xor(a0, 32);
  a1 += __shfl_xor(a1, 16); a1 += __shfl_xor(a1, 32);
  a2 += __shfl_xor(a2, 16); a2 += __shfl_xor(a2, 32);
  a3 += __shfl_xor(a3, 16); a3 += __shfl_xor(a3, 32);

  if (slot == 0) {
    const float inv = 1.0f / (denA[dst] + 1e-16f);
    const bool f = flags[0] != 0;
    float b0, b1, b2, b3;
    if (f) {
      b0 = loadF<true>(bias, 4 * el + 0); b1 = loadF<true>(bias, 4 * el + 1);
      b2 = loadF<true>(bias, 4 * el + 2); b3 = loadF<true>(bias, 4 * el + 3);
    } else {
      b0 = loadF<false>(bias, 4 * el + 0); b1 = loadF<false>(bias, 4 * el + 1);
      b2 = loadF<false>(bias, 4 * el + 2); b3 = loadF<false>(bias, 4 * el + 3);
    }
    float o0 = a0 * inv + b0, o1 = a1 * inv + b1;
    float o2 = a2 * inv + b2, o3 = a3 * inv + b3;
    size_t ob = (size_t)dst * 64 + 4 * el;
    if (f) {
      ushort4 ov;
      ov.x = f2bfbits(o0); ov.y = f2bfbits(o1);
      ov.z = f2bfbits(o2); ov.w = f2bfbits(o3);
      *(ushort4*)((unsigned short*)out + ob) = ov;
    } else {
      float4 ov; ov.x = o0; ov.y = o1; ov.z = o2; ov.w = o3;
      *(float4*)((float*)out + ob) = ov;
    }
  }
}

// ---------------------------------------------------------------------------
extern "C" void kernel_launch(void* const* d_in, const int* in_sizes, int n_in,
                              void* d_out, int out_size, void* d_ws, size_t ws_size,
                              hipStream_t stream) {
  const void* x    = d_in[0];
  const void* ei   = d_in[1];
  const void* W1   = d_in[2];
  const void* as1w = d_in[3];
  const void* ad1w = d_in[4];
  const void* b1   = d_in[5];
  const void* W2   = d_in[6];
  const void* as2w = d_in[7];
  const void* ad2w = d_in[8];
  const void* b2   = d_in[9];

  const int N  = out_size / 64;      // 50000
  const int F  = in_sizes[0] / N;    // 128
  const int E  = in_sizes[1] / 2;    // 800000
  const int H1 = in_sizes[3] / 64;   // 4
  const int D1 = H1 * 64;            // 256
  const int D2 = 64;                 // layer-2 output dim (H2 = 1)

  size_t off = 0;
  auto alloc = [&](size_t bytes) -> void* {
    void* p = (char*)d_ws + off;
    off += (bytes + 255) & ~(size_t)255;
    return p;
  };
  int* flags = (int*)alloc(2 * sizeof(int));
  __hip_bfloat16* h1 = (__hip_bfloat16*)alloc((size_t)N * D1 * 2);
  __hip_bfloat16* x2 = (__hip_bfloat16*)alloc((size_t)N * D1 * 2);
  __hip_bfloat16* h2 = h1;  // h1 dead after layer-1 aggregate; reuse
  unsigned short* xb  = (unsigned short*)alloc((size_t)N * F * 2);   // x in bf16
  unsigned short* w1t = (unsigned short*)alloc((size_t)D1 * F * 2);  // [256][128]
  unsigned short* w2t = (unsigned short*)alloc((size_t)D2 * D1 * 2); // [64][256]
  float* as1 = (float*)alloc((size_t)N * H1 * 4);
  float* ad1 = (float*)alloc((size_t)N * H1 * 4);
  float* wself1 = (float*)alloc((size_t)N * H1 * 4);
  float* den1 = (float*)alloc((size_t)N * H1 * 4);
  float* as2 = (float*)alloc((size_t)N * 4);
  float* ad2 = (float*)alloc((size_t)N * 4);
  float* wself2 = (float*)alloc((size_t)N * 4);
  float* den2 = (float*)alloc((size_t)N * 4);
  int* zero_region = (int*)alloc((size_t)2 * N * 4);  // deg | cursor
  int* deg = zero_region;
  int* cursor = zero_region + N;
  int* row_start = (int*)alloc((size_t)(N + 1) * 4);
  int* col_src = (int*)alloc((size_t)E * 4);
  float* wbuf = (float*)alloc((size_t)E * 4 * 4);  // L1: [E]float4; L2 reuses [E]float
  int* bsum = (int*)alloc((size_t)256 * 4);
  (void)ws_size; (void)n_in;

  const int nb = (N + 255) / 256;
  const int eb = (E + 255) / 256;
  const int db = (N + 3) / 4;
  const int gb = (N + 63) / 64;

  // ---- dtype detection + CSR build + GEMM prep (single prep dispatch)
  detect_kernel<<<1, 64, 0, stream>>>((const uint32_t*)x, (const uint32_t*)ei, flags);
  hipMemsetAsync(zero_region, 0, (size_t)2 * N * 4, stream);
  hist_kernel<<<eb, 256, 0, stream>>>(ei, E, deg, flags);
  scan_block_sums<<<nb, 256, 0, stream>>>(deg, bsum, N);
  scan_bsums<<<1, 256, 0, stream>>>(bsum, nb);
  scan_finalize<<<nb, 256, 0, stream>>>(deg, bsum, row_start, N);
  scatter_edges<<<eb, 256, 0, stream>>>(ei, E, row_start, cursor, col_src, flags);

  const size_t nx = (size_t)N * F;
  const int nb_cast = (int)((nx / 4 + 255) / 256);
  const int nb_t1 = (F * D1 + 255) / 256;
  const int nb_t2 = (D1 * D2 + 255) / 256;
  prep_all<<<nb_cast + nb_t1 + nb_t2, 256, 0, stream>>>(
      x, xb, nx, W1, w1t, F, D1, W2, w2t, D1, D2, nb_cast, nb_t1, flags);

  // ---- layer 1: GEMM 64x128 tiles (grid.y = 2), K=128 unrolled
  gemm_mfma_att<128, 8, 2><<<dim3(gb, 2), 256, 0, stream>>>(
      xb, w1t, (unsigned short*)h1, as1w, ad1w, as1, ad1, wself1, N, H1, flags);
  softmax_den4<<<db, 256, 0, stream>>>((const float4*)as1, (const float4*)ad1,
                                       row_start, col_src, (const float4*)wself1,
                                       (float4*)wbuf, (float4*)den1, N);
  aggregate4<<<db, 256, 0, stream>>>((const unsigned short*)h1, wself1, den1, wbuf,
                                     row_start, col_src, b1,
                                     (unsigned short*)x2, N, flags);

  // ---- layer 2: GEMM 64x64 tile, K=256 unrolled
  gemm_mfma_att<256, 4, 1><<<dim3(gb, 1), 256, 0, stream>>>(
      (const unsigned short*)x2, w2t, (unsigned short*)h2, as2w, ad2w,
      as2, ad2, wself2, N, 1, flags);
  softmax_den1<<<db, 256, 0, stream>>>(as2, ad2, row_start, col_src, wself2,
                                       wbuf, den2, N);
  aggregate1<<<db, 256, 0, stream>>>((const unsigned short*)h2, wself2, den2, wbuf,
                                     row_start, col_src, b2, d_out, N, flags);
}

// Round 14
// 349.850 us; speedup vs baseline: 1.1500x; 1.0563x over previous
//
#include <hip/hip_runtime.h>
#include <hip/hip_bf16.h>
#include <stdint.h>

// ---------------------------------------------------------------------------
// 2-layer GAT (inference) on MI355X, dtype-adaptive.
// Round-14 changes vs round-13 (369.6 us):
//  * softmax_den4/den1 (wave-per-dst, ~75% idle lanes at avg deg 17) replaced
//    by edge-parallel weight4/weight1 (coalesced map; col_dst restored in
//    scatter). No per-dst loops, no reductions.
//  * Denominator computed inline in the aggregates from the streamed wbuf
//    values (aggregate4: all lanes of a head sum identical p; aggregate1:
//    per-slot partials ride the existing shfl_xor(16/32) reduction).
// Everything else byte-identical to round 13.
// ---------------------------------------------------------------------------

typedef __attribute__((ext_vector_type(8))) short bf16x8;
typedef __attribute__((ext_vector_type(4))) float f32x4;

__device__ __forceinline__ float bf2f(__hip_bfloat16 v) { return __bfloat162float(v); }
__device__ __forceinline__ float bfbits2f(unsigned short s) {
  union { uint32_t u; float f; } v; v.u = ((uint32_t)s) << 16; return v.f;
}
__device__ __forceinline__ unsigned short f2bfbits(float f) {
  union { float f; uint32_t u; } v; v.f = f;
  uint32_t u = v.u;
  return (unsigned short)((u + 0x7fffu + ((u >> 16) & 1u)) >> 16);  // RNE
}

template <bool BF>
__device__ __forceinline__ float loadF(const void* p, size_t i) {
  if (BF) return bf2f(((const __hip_bfloat16*)p)[i]);
  return ((const float*)p)[i];
}
template <bool BF>
__device__ __forceinline__ void storeF(void* p, size_t i, float v) {
  if (BF) ((__hip_bfloat16*)p)[i] = __float2bfloat16(v);
  else    ((float*)p)[i] = v;
}
template <bool I64>
__device__ __forceinline__ int loadI(const void* p, size_t i) {
  if (I64) return (int)((const long long*)p)[i];
  return ((const int*)p)[i];
}
__device__ __forceinline__ float lrelu(float v) { return fmaxf(v, 0.2f * v); }

// ----------------- dtype detection (1 thread) ------------------------------
__global__ void detect_kernel(const uint32_t* __restrict__ xbits,
                              const uint32_t* __restrict__ eibits,
                              int* __restrict__ flags) {
  if (threadIdx.x != 0 || blockIdx.x != 0) return;
  int plausible = 0;
  for (int i = 0; i < 64; i++) {
    uint32_t u = xbits[i];
    uint32_t e = (u >> 23) & 0xffu;
    if ((e < 160u && e > 90u) || (u & 0x7fffffffu) == 0u) plausible++;
  }
  flags[0] = (plausible < 32) ? 1 : 0;  // 1 = floats are bf16
  int allz = 1;
  for (int i = 0; i < 64; i++)
    if (eibits[2 * i + 1] != 0u) allz = 0;
  flags[1] = allz;                      // 1 = edge_index is int64
}

// ----------------- prep (single dispatch): cast x; transpose W1, W2 --------
__global__ __launch_bounds__(256) void prep_all(
    const void* __restrict__ x, unsigned short* __restrict__ xb, size_t nx,
    const void* __restrict__ W1, unsigned short* __restrict__ w1t, int K1, int N1,
    const void* __restrict__ W2, unsigned short* __restrict__ w2t, int K2, int N2,
    int nb_cast, int nb_t1, const int* __restrict__ flags) {
  const int b = blockIdx.x;
  const bool f = flags[0] != 0;
  if (b < nb_cast) {
    size_t i = ((size_t)b * 256 + threadIdx.x) * 4;
    if (i >= nx) return;
    ushort4 o;
    if (f) {
      o = *(const ushort4*)((const unsigned short*)x + i);
    } else {
      float4 v = *(const float4*)((const float*)x + i);
      o.x = f2bfbits(v.x); o.y = f2bfbits(v.y);
      o.z = f2bfbits(v.z); o.w = f2bfbits(v.w);
    }
    *(ushort4*)(xb + i) = o;
  } else if (b < nb_cast + nb_t1) {
    int idx = (b - nb_cast) * 256 + threadIdx.x;
    if (idx >= K1 * N1) return;
    int k = idx / N1, n = idx - k * N1;
    float v = f ? loadF<true>(W1, idx) : loadF<false>(W1, idx);
    w1t[(size_t)n * K1 + k] = f2bfbits(v);
  } else {
    int idx = (b - nb_cast - nb_t1) * 256 + threadIdx.x;
    if (idx >= K2 * N2) return;
    int k = idx / N2, n = idx - k * N2;
    float v = f ? loadF<true>(W2, idx) : loadF<false>(W2, idx);
    w2t[(size_t)n * K2 + k] = f2bfbits(v);
  }
}

// ----------------- MFMA GEMM + fused attention-dot epilogue ----------------
template <int KC, int NT, int HB>
__global__ __launch_bounds__(256, 4) void gemm_mfma_att(
    const unsigned short* __restrict__ A,   // [M][KC] bf16 bits
    const unsigned short* __restrict__ BT,  // [Htot*64][KC] bf16 bits
    unsigned short* __restrict__ C,         // [M][Htot*64] bf16 bits
    const void* __restrict__ att_s, const void* __restrict__ att_d,
    float* __restrict__ as_o, float* __restrict__ ad_o,
    float* __restrict__ wself_o,
    int M, int Htot, const int* __restrict__ flags) {
  const int lane = threadIdx.x & 63;
  const int col = lane & 15;
  const int quad = lane >> 4;
  const int m0 = blockIdx.x * 64 + (threadIdx.x >> 6) * 16;
  const int n0 = blockIdx.y * (NT * 16);
  const int NCOL = Htot * 64;

  int gm = m0 + col;                 // A row this lane supplies
  if (gm > M - 1) gm = M - 1;        // clamp: garbage only affects guarded rows
  const unsigned short* arow = A + (size_t)gm * KC + quad * 8;
  const unsigned short* bbase = BT + (size_t)(n0 + col) * KC + quad * 8;

  f32x4 acc[NT] = {};
#pragma unroll
  for (int k0 = 0; k0 < KC; k0 += 32) {
    bf16x8 a = *(const bf16x8*)(arow + k0);
#pragma unroll
    for (int s = 0; s < NT; s++) {
      bf16x8 b = *(const bf16x8*)(bbase + (size_t)s * 16 * KC + k0);
      acc[s] = __builtin_amdgcn_mfma_f32_16x16x32_bf16(a, b, acc[s], 0, 0, 0);
    }
  }
  // store C
#pragma unroll
  for (int s = 0; s < NT; s++)
#pragma unroll
    for (int r = 0; r < 4; r++) {
      int m = m0 + quad * 4 + r;
      if (m < M) C[(size_t)m * NCOL + n0 + s * 16 + col] = f2bfbits(acc[s][r]);
    }
  // fused attention dots: head h covers s in [h*SC, (h+1)*SC)
  const int SC = NT / HB;
  const bool f = flags[0] != 0;
#pragma unroll
  for (int h = 0; h < HB; h++) {
    const int gh = blockIdx.y * HB + h;
    float ps[4] = {0.f, 0.f, 0.f, 0.f};
    float pd[4] = {0.f, 0.f, 0.f, 0.f};
#pragma unroll
    for (int j = 0; j < SC; j++) {
      int s = h * SC + j;
      int ci = gh * 64 + j * 16 + col;
      float av = f ? loadF<true>(att_s, ci) : loadF<false>(att_s, ci);
      float dv = f ? loadF<true>(att_d, ci) : loadF<false>(att_d, ci);
#pragma unroll
      for (int r = 0; r < 4; r++) {
        ps[r] += acc[s][r] * av;
        pd[r] += acc[s][r] * dv;
      }
    }
#pragma unroll
    for (int o = 1; o < 16; o <<= 1) {
#pragma unroll
      for (int r = 0; r < 4; r++) {
        ps[r] += __shfl_xor(ps[r], o);
        pd[r] += __shfl_xor(pd[r], o);
      }
    }
    if (col == 0) {
#pragma unroll
      for (int r = 0; r < 4; r++) {
        int m = m0 + quad * 4 + r;
        if (m < M) {
          as_o[m * Htot + gh] = ps[r];
          ad_o[m * Htot + gh] = pd[r];
          wself_o[m * Htot + gh] = __expf(lrelu(ps[r] + pd[r]));  // no max-sub
        }
      }
    }
  }
}

// ----------------- CSR build ------------------------------------------------
__global__ void hist_kernel(const void* __restrict__ ei, int E,
                            int* __restrict__ deg, const int* __restrict__ flags) {
  int e = blockIdx.x * blockDim.x + threadIdx.x;
  if (e >= E) return;
  int d = flags[1] ? loadI<true>(ei, (size_t)E + e) : loadI<false>(ei, (size_t)E + e);
  atomicAdd(&deg[d], 1);
}

__global__ __launch_bounds__(256) void scan_block_sums(const int* __restrict__ deg,
                                                       int* __restrict__ bsum, int n) {
  __shared__ int buf[256];
  const int t = threadIdx.x;
  const int i = blockIdx.x * 256 + t;
  buf[t] = (i < n) ? deg[i] : 0;
  __syncthreads();
  for (int o = 128; o > 0; o >>= 1) {
    if (t < o) buf[t] += buf[t + o];
    __syncthreads();
  }
  if (t == 0) bsum[blockIdx.x] = buf[0];
}

__global__ __launch_bounds__(256) void scan_bsums(int* __restrict__ bsum, int nb) {
  __shared__ int buf[256];
  const int t = threadIdx.x;
  int orig = (t < nb) ? bsum[t] : 0;
  buf[t] = orig;
  __syncthreads();
  for (int o = 1; o < 256; o <<= 1) {
    int v = (t >= o) ? buf[t - o] : 0;
    __syncthreads();
    buf[t] += v;
    __syncthreads();
  }
  if (t < nb) bsum[t] = buf[t] - orig;  // exclusive
}

__global__ __launch_bounds__(256) void scan_finalize(const int* __restrict__ deg,
                                                     const int* __restrict__ bsum,
                                                     int* __restrict__ row_start, int n) {
  __shared__ int buf[256];
  const int t = threadIdx.x;
  const int i = blockIdx.x * 256 + t;
  int v = (i < n) ? deg[i] : 0;
  buf[t] = v;
  __syncthreads();
  for (int o = 1; o < 256; o <<= 1) {
    int x = (t >= o) ? buf[t - o] : 0;
    __syncthreads();
    buf[t] += x;
    __syncthreads();
  }
  if (i < n) row_start[i + 1] = bsum[blockIdx.x] + buf[t];
  if (i == 0) row_start[0] = 0;
}

__global__ void scatter_edges(const void* __restrict__ ei, int E,
                              const int* __restrict__ row_start,
                              int* __restrict__ cursor, int* __restrict__ col_src,
                              int* __restrict__ col_dst,
                              const int* __restrict__ flags) {
  int e = blockIdx.x * blockDim.x + threadIdx.x;
  if (e >= E) return;
  int s, d;
  if (flags[1]) { s = loadI<true>(ei, e);  d = loadI<true>(ei, (size_t)E + e); }
  else          { s = loadI<false>(ei, e); d = loadI<false>(ei, (size_t)E + e); }
  int pos = atomicAdd(&cursor[d], 1);
  int idx = row_start[d] + pos;
  col_src[idx] = s;
  col_dst[idx] = d;
}

// ----------------- edge-parallel softmax weights (coalesced map) -----------
__global__ __launch_bounds__(256) void weight4(
    const int* __restrict__ col_src, const int* __restrict__ col_dst,
    const float4* __restrict__ as4, const float4* __restrict__ ad4,
    float4* __restrict__ wbuf, int E) {
  int e = blockIdx.x * 256 + threadIdx.x;
  if (e >= E) return;
  float4 a = as4[col_src[e]];
  float4 b = ad4[col_dst[e]];
  float4 w;
  w.x = __expf(lrelu(a.x + b.x));
  w.y = __expf(lrelu(a.y + b.y));
  w.z = __expf(lrelu(a.z + b.z));
  w.w = __expf(lrelu(a.w + b.w));
  wbuf[e] = w;
}

__global__ __launch_bounds__(256) void weight1(
    const int* __restrict__ col_src, const int* __restrict__ col_dst,
    const float* __restrict__ as_, const float* __restrict__ ad_,
    float* __restrict__ wbuf, int E) {
  int e = blockIdx.x * 256 + threadIdx.x;
  if (e >= E) return;
  wbuf[e] = __expf(lrelu(as_[col_src[e]] + ad_[col_dst[e]]));
}

// ----------------- aggregation: weighted gather + inline denominator -------
// H=4 (round-9 proven body; p summed inline from streamed w)
__global__ __launch_bounds__(256) void aggregate4(
    const unsigned short* __restrict__ h_in,   // [N][256] bf16 bits
    const float* __restrict__ wselfA,
    const float* __restrict__ wbuf,            // [E][4]
    const int* __restrict__ row_start, const int* __restrict__ col_src,
    const void* __restrict__ bias,
    unsigned short* __restrict__ out,          // [N][256] bf16 bits (x2)
    int N, const int* __restrict__ flags) {
  const int dst = blockIdx.x * 4 + (threadIdx.x >> 6);
  if (dst >= N) return;
  const int l = threadIdx.x & 63;
  const int h = l >> 4;
  const int rs = row_start[dst];
  const int dg = row_start[dst + 1] - rs;
  const float ws = wselfA[dst * 4 + h];

  float a0, a1, a2, a3;
  {
    ushort4 sv = *(const ushort4*)(h_in + (size_t)dst * 256 + 4 * l);
    a0 = ws * bfbits2f(sv.x);
    a1 = ws * bfbits2f(sv.y);
    a2 = ws * bfbits2f(sv.z);
    a3 = ws * bfbits2f(sv.w);
  }
  float p = 0.f;
#pragma unroll 4
  for (int i = 0; i < dg; i++) {
    int sn = col_src[rs + i];
    float w = wbuf[(size_t)(rs + i) * 4 + h];
    p += w;
    ushort4 sv = *(const ushort4*)(h_in + (size_t)sn * 256 + 4 * l);
    a0 += w * bfbits2f(sv.x);
    a1 += w * bfbits2f(sv.y);
    a2 += w * bfbits2f(sv.z);
    a3 += w * bfbits2f(sv.w);
  }
  const float inv = 1.0f / (p + ws + 1e-16f);
  const bool f = flags[0] != 0;
  float b0, b1, b2, b3;
  if (f) {
    b0 = loadF<true>(bias, 4 * l + 0); b1 = loadF<true>(bias, 4 * l + 1);
    b2 = loadF<true>(bias, 4 * l + 2); b3 = loadF<true>(bias, 4 * l + 3);
  } else {
    b0 = loadF<false>(bias, 4 * l + 0); b1 = loadF<false>(bias, 4 * l + 1);
    b2 = loadF<false>(bias, 4 * l + 2); b3 = loadF<false>(bias, 4 * l + 3);
  }
  float o0 = a0 * inv + b0, o1 = a1 * inv + b1;
  float o2 = a2 * inv + b2, o3 = a3 * inv + b3;
  o0 = o0 > 0.f ? o0 : __expf(o0) - 1.f;
  o1 = o1 > 0.f ? o1 : __expf(o1) - 1.f;
  o2 = o2 > 0.f ? o2 : __expf(o2) - 1.f;
  o3 = o3 > 0.f ? o3 : __expf(o3) - 1.f;
  ushort4 ov;
  ov.x = f2bfbits(o0); ov.y = f2bfbits(o1); ov.z = f2bfbits(o2); ov.w = f2bfbits(o3);
  *(ushort4*)(out + (size_t)dst * 256 + 4 * l) = ov;
}

// H=1: slot layout; p partials per slot ride the shfl_xor(16/32) reduction.
__global__ __launch_bounds__(256) void aggregate1(
    const unsigned short* __restrict__ h_in,   // [N][64] bf16 bits
    const float* __restrict__ wselfA,
    const float* __restrict__ wbuf,            // [E]
    const int* __restrict__ row_start, const int* __restrict__ col_src,
    const void* __restrict__ bias,
    void* __restrict__ out, int N, const int* __restrict__ flags) {
  const int dst = blockIdx.x * 4 + (threadIdx.x >> 6);
  if (dst >= N) return;
  const int l = threadIdx.x & 63;
  const int el = l & 15;
  const int slot = l >> 4;
  const int rs = row_start[dst];
  const int dg = row_start[dst + 1] - rs;
  const float ws = wselfA[dst];

  float a0 = 0.f, a1 = 0.f, a2 = 0.f, a3 = 0.f, p = 0.f;
  if (slot == 0) {
    ushort4 sv = *(const ushort4*)(h_in + (size_t)dst * 64 + 4 * el);
    a0 = ws * bfbits2f(sv.x);
    a1 = ws * bfbits2f(sv.y);
    a2 = ws * bfbits2f(sv.z);
    a3 = ws * bfbits2f(sv.w);
  }
#pragma unroll 2
  for (int i = slot; i < dg; i += 4) {
    int sn = col_src[rs + i];
    float w = wbuf[rs + i];
    p += w;
    ushort4 sv = *(const ushort4*)(h_in + (size_t)sn * 64 + 4 * el);
    a0 += w * bfbits2f(sv.x);
    a1 += w * bfbits2f(sv.y);
    a2 += w * bfbits2f(sv.z);
    a3 += w * bfbits2f(sv.w);
  }
  a0 += __shfl_xor(a0, 16); a0 += __shfl_xor(a0, 32);
  a1 += __shfl_xor(a1, 16); a1 += __shfl_xor(a1, 32);
  a2 += __shfl_xor(a2, 16); a2 += __shfl_xor(a2, 32);
  a3 += __shfl_xor(a3, 16); a3 += __shfl_xor(a3, 32);
  p  += __shfl_xor(p, 16);  p  += __shfl_xor(p, 32);

  if (slot == 0) {
    // p now holds the sum over this el-column's 4 slots; note all el share
    // the same full-edge sum only after combining slots — p here is the sum
    // over slots {0..3} for edges i ≡ slot (mod 4), i.e. ALL edges. Correct.
    const float inv = 1.0f / (p + ws + 1e-16f);
    const bool f = flags[0] != 0;
    float b0, b1, b2, b3;
    if (f) {
      b0 = loadF<true>(bias, 4 * el + 0); b1 = loadF<true>(bias, 4 * el + 1);
      b2 = loadF<true>(bias, 4 * el + 2); b3 = loadF<true>(bias, 4 * el + 3);
    } else {
      b0 = loadF<false>(bias, 4 * el + 0); b1 = loadF<false>(bias, 4 * el + 1);
      b2 = loadF<false>(bias, 4 * el + 2); b3 = loadF<false>(bias, 4 * el + 3);
    }
    float o0 = a0 * inv + b0, o1 = a1 * inv + b1;
    float o2 = a2 * inv + b2, o3 = a3 * inv + b3;
    size_t ob = (size_t)dst * 64 + 4 * el;
    if (f) {
      ushort4 ov;
      ov.x = f2bfbits(o0); ov.y = f2bfbits(o1);
      ov.z = f2bfbits(o2); ov.w = f2bfbits(o3);
      *(ushort4*)((unsigned short*)out + ob) = ov;
    } else {
      float4 ov; ov.x = o0; ov.y = o1; ov.z = o2; ov.w = o3;
      *(float4*)((float*)out + ob) = ov;
    }
  }
}

// ---------------------------------------------------------------------------
extern "C" void kernel_launch(void* const* d_in, const int* in_sizes, int n_in,
                              void* d_out, int out_size, void* d_ws, size_t ws_size,
                              hipStream_t stream) {
  const void* x    = d_in[0];
  const void* ei   = d_in[1];
  const void* W1   = d_in[2];
  const void* as1w = d_in[3];
  const void* ad1w = d_in[4];
  const void* b1   = d_in[5];
  const void* W2   = d_in[6];
  const void* as2w = d_in[7];
  const void* ad2w = d_in[8];
  const void* b2   = d_in[9];

  const int N  = out_size / 64;      // 50000
  const int F  = in_sizes[0] / N;    // 128
  const int E  = in_sizes[1] / 2;    // 800000
  const int H1 = in_sizes[3] / 64;   // 4
  const int D1 = H1 * 64;            // 256
  const int D2 = 64;                 // layer-2 output dim (H2 = 1)

  size_t off = 0;
  auto alloc = [&](size_t bytes) -> void* {
    void* p = (char*)d_ws + off;
    off += (bytes + 255) & ~(size_t)255;
    return p;
  };
  int* flags = (int*)alloc(2 * sizeof(int));
  __hip_bfloat16* h1 = (__hip_bfloat16*)alloc((size_t)N * D1 * 2);
  __hip_bfloat16* x2 = (__hip_bfloat16*)alloc((size_t)N * D1 * 2);
  __hip_bfloat16* h2 = h1;  // h1 dead after layer-1 aggregate; reuse
  unsigned short* xb  = (unsigned short*)alloc((size_t)N * F * 2);   // x in bf16
  unsigned short* w1t = (unsigned short*)alloc((size_t)D1 * F * 2);  // [256][128]
  unsigned short* w2t = (unsigned short*)alloc((size_t)D2 * D1 * 2); // [64][256]
  float* as1 = (float*)alloc((size_t)N * H1 * 4);
  float* ad1 = (float*)alloc((size_t)N * H1 * 4);
  float* wself1 = (float*)alloc((size_t)N * H1 * 4);
  float* as2 = (float*)alloc((size_t)N * 4);
  float* ad2 = (float*)alloc((size_t)N * 4);
  float* wself2 = (float*)alloc((size_t)N * 4);
  int* zero_region = (int*)alloc((size_t)2 * N * 4);  // deg | cursor
  int* deg = zero_region;
  int* cursor = zero_region + N;
  int* row_start = (int*)alloc((size_t)(N + 1) * 4);
  int* col_src = (int*)alloc((size_t)E * 4);
  int* col_dst = (int*)alloc((size_t)E * 4);
  float* wbuf = (float*)alloc((size_t)E * 4 * 4);  // L1: [E]float4; L2 reuses [E]float
  int* bsum = (int*)alloc((size_t)256 * 4);
  (void)ws_size; (void)n_in;

  const int nb = (N + 255) / 256;
  const int eb = (E + 255) / 256;
  const int db = (N + 3) / 4;
  const int gb = (N + 63) / 64;

  // ---- dtype detection + CSR build + GEMM prep (single prep dispatch)
  detect_kernel<<<1, 64, 0, stream>>>((const uint32_t*)x, (const uint32_t*)ei, flags);
  hipMemsetAsync(zero_region, 0, (size_t)2 * N * 4, stream);
  hist_kernel<<<eb, 256, 0, stream>>>(ei, E, deg, flags);
  scan_block_sums<<<nb, 256, 0, stream>>>(deg, bsum, N);
  scan_bsums<<<1, 256, 0, stream>>>(bsum, nb);
  scan_finalize<<<nb, 256, 0, stream>>>(deg, bsum, row_start, N);
  scatter_edges<<<eb, 256, 0, stream>>>(ei, E, row_start, cursor, col_src, col_dst, flags);

  const size_t nx = (size_t)N * F;
  const int nb_cast = (int)((nx / 4 + 255) / 256);
  const int nb_t1 = (F * D1 + 255) / 256;
  const int nb_t2 = (D1 * D2 + 255) / 256;
  prep_all<<<nb_cast + nb_t1 + nb_t2, 256, 0, stream>>>(
      x, xb, nx, W1, w1t, F, D1, W2, w2t, D1, D2, nb_cast, nb_t1, flags);

  // ---- layer 1: GEMM 64x128 tiles (grid.y = 2), K=128 unrolled
  gemm_mfma_att<128, 8, 2><<<dim3(gb, 2), 256, 0, stream>>>(
      xb, w1t, (unsigned short*)h1, as1w, ad1w, as1, ad1, wself1, N, H1, flags);
  weight4<<<eb, 256, 0, stream>>>(col_src, col_dst, (const float4*)as1,
                                  (const float4*)ad1, (float4*)wbuf, E);
  aggregate4<<<db, 256, 0, stream>>>((const unsigned short*)h1, wself1, wbuf,
                                     row_start, col_src, b1,
                                     (unsigned short*)x2, N, flags);

  // ---- layer 2: GEMM 64x64 tile, K=256 unrolled
  gemm_mfma_att<256, 4, 1><<<dim3(gb, 1), 256, 0, stream>>>(
      (const unsigned short*)x2, w2t, (unsigned short*)h2, as2w, ad2w,
      as2, ad2, wself2, N, 1, flags);
  weight1<<<eb, 256, 0, stream>>>(col_src, col_dst, as2, ad2, wbuf, E);
  aggregate1<<<db, 256, 0, stream>>>((const unsigned short*)h2, wself2, wbuf,
                                     row_start, col_src, b2, d_out, N, flags);
}